// Round 2
// baseline (10402.418 us; speedup 1.0000x reference)
//
#include <hip/hip_runtime.h>
#include <hip/hip_bf16.h>

// FrequencyInflammationDetector — round 2 resubmit (round-1 infra timeout).
// Correct fp32-compute baseline, MFMA-ready layouts (NHWC activations,
// [k][oc] BN-folded weights, fused concat). Workspace aliased to 805 MB peak.
//
// Pipeline:
//  K_repack x6 : fold BN into weights -> wrep[k][oc], brep[oc]
//  K_front     : x(NCHW f32) -> 1x1 conv(3->16) relu -> 1x1(16->3) -> Haar ->
//                low (NHWC f32, C=3), high (NHWC f32, C=9) at 256x256
//  K_conv3x3   : generic 3x3+BN+relu, LDS input tile [CIN][18][19]
//                lconv1: low(3)->lf1(64,bf16); hconv1: high(9)->hf1(64,bf16)
//                lconv2: lf1->fcat[ch 0..127]; hconv2: hf1->fcat[ch 128..255]
//  K_conv1x1   : fconv1: fcat(256)->f1(128,bf16); fconv2: f1(128)->out(NCHW f32)

#define EPS_BN 1e-5f

typedef unsigned int u32;
typedef unsigned short u16;

__device__ __forceinline__ float bflo(u32 u) { return __uint_as_float(u << 16); }
__device__ __forceinline__ float bfhi(u32 u) { return __uint_as_float(u & 0xffff0000u); }
__device__ __forceinline__ u16 f2bf(float f) {
  u32 u = __float_as_uint(f);
  u32 r = (u + 0x7fffu + ((u >> 16) & 1u)) >> 16;   // RNE
  return (u16)r;
}

// ---------------- weight repack: wrep[k*COUT+oc] = w[oc*K+k]*alpha, brep = b*alpha + (be - m*alpha)
__global__ __launch_bounds__(256) void repack_kernel(
    const float* __restrict__ w, const float* __restrict__ bias,
    const float* __restrict__ g, const float* __restrict__ be,
    const float* __restrict__ m, const float* __restrict__ v,
    float* __restrict__ wrep, float* __restrict__ brep, int K, int COUT)
{
  int idx = blockIdx.x * 256 + threadIdx.x;
  if (idx < K * COUT) {
    int oc = idx % COUT;
    int k  = idx / COUT;
    float alpha = g[oc] * rsqrtf(v[oc] + EPS_BN);
    wrep[idx] = w[(size_t)oc * K + k] * alpha;
  }
  if (idx < COUT) {
    float alpha = g[idx] * rsqrtf(v[idx] + EPS_BN);
    brep[idx] = fmaf(bias[idx], alpha, be[idx] - m[idx] * alpha);
  }
}

// ---------------- front: 1x1 conv -> relu -> 1x1 conv -> haar DWT
__global__ __launch_bounds__(256) void front_kernel(
    const float* __restrict__ x,
    const float* __restrict__ cw1, const float* __restrict__ cb1,
    const float* __restrict__ cw2, const float* __restrict__ cb2,
    float* __restrict__ low, float* __restrict__ high)
{
  const int pid = blockIdx.x * 256 + threadIdx.x;   // 0 .. 16*256*256-1
  const int wo = pid & 255, ho = (pid >> 8) & 255, b = pid >> 16;
  float hsv[2][2][3];
  #pragma unroll
  for (int dy = 0; dy < 2; ++dy) {
    #pragma unroll
    for (int dx = 0; dx < 2; ++dx) {
      int h = 2 * ho + dy, w = 2 * wo + dx;
      size_t base = ((size_t)(b * 3) << 18) + (size_t)h * 512 + w; // 512*512 = 1<<18
      float p0 = x[base];
      float p1 = x[base + (1u << 18)];
      float p2 = x[base + (2u << 18)];
      float o0 = cb2[0], o1 = cb2[1], o2 = cb2[2];
      #pragma unroll
      for (int o = 0; o < 16; ++o) {
        float t = fmaf(cw1[o*3+2], p2, fmaf(cw1[o*3+1], p1, fmaf(cw1[o*3+0], p0, cb1[o])));
        t = fmaxf(t, 0.f);
        o0 = fmaf(cw2[o],      t, o0);
        o1 = fmaf(cw2[16 + o], t, o1);
        o2 = fmaf(cw2[32 + o], t, o2);
      }
      hsv[dy][dx][0] = o0; hsv[dy][dx][1] = o1; hsv[dy][dx][2] = o2;
    }
  }
  size_t lb = (size_t)pid * 3;
  size_t hb = (size_t)pid * 9;
  #pragma unroll
  for (int c = 0; c < 3; ++c) {
    float a  = hsv[0][0][c], bb = hsv[0][1][c];
    float cc = hsv[1][0][c], dd = hsv[1][1][c];
    low [lb + c]         = (a + bb + cc + dd) * 0.5f;
    high[hb + c*3 + 0]   = (a + bb - cc - dd) * 0.5f;
    high[hb + c*3 + 1]   = (a - bb + cc - dd) * 0.5f;
    high[hb + c*3 + 2]   = (a - bb - cc + dd) * 0.5f;
  }
}

// ---------------- generic 3x3 conv + folded BN + relu (pad=1), NHWC in/out
template<int CIN, int COUT, bool IN_BF16>
__global__ __launch_bounds__(256, 1) void conv3x3_bn_relu(
    const void* __restrict__ in_, const float* __restrict__ wrep,
    const float* __restrict__ brep, u16* __restrict__ out,
    int out_stride, int out_choff)
{
  constexpr int EB = IN_BF16 ? 2 : 4;
  __shared__ __align__(16) unsigned char smem[(size_t)CIN * 18 * 19 * EB];
  const int tid = threadIdx.x;
  const int tx = tid & 15, ty = tid >> 4;
  const int w0 = blockIdx.x * 16, h0 = blockIdx.y * 16, b = blockIdx.z;

  // stage input tile: tile[ic][y][x] = in[b, h0-1+y, w0-1+x, ic] (0 pad OOB)
  for (int idx = tid; idx < 18 * 18 * CIN; idx += 256) {
    int ic = idx % CIN;
    int t  = idx / CIN;
    int x  = t % 18, y = t / 18;
    int gy = h0 + y - 1, gx = w0 + x - 1;
    bool ok = (gy >= 0 && gy < 256 && gx >= 0 && gx < 256);
    size_t gaddr = (size_t)((b * 256 + gy) * 256 + gx) * CIN + ic;
    if constexpr (IN_BF16) {
      u16* tile = (u16*)smem;
      u16 val = ok ? ((const u16*)in_)[gaddr] : (u16)0;
      tile[(ic * 18 + y) * 19 + x] = val;
    } else {
      float* tile = (float*)smem;
      float val = ok ? ((const float*)in_)[gaddr] : 0.f;
      tile[(ic * 18 + y) * 19 + x] = val;
    }
  }
  __syncthreads();

  const size_t pix = (size_t)((b * 256 + (h0 + ty)) * 256 + (w0 + tx));
  constexpr int NG = COUT / 16;
  for (int gr = 0; gr < NG; ++gr) {
    float acc[16];
    #pragma unroll
    for (int j = 0; j < 16; ++j) acc[j] = 0.f;
    for (int ic = 0; ic < CIN; ++ic) {
      #pragma unroll
      for (int ky = 0; ky < 3; ++ky) {
        #pragma unroll
        for (int kx = 0; kx < 3; ++kx) {
          float a;
          if constexpr (IN_BF16) {
            const u16* tile = (const u16*)smem;
            a = __uint_as_float((u32)tile[(ic * 18 + (ty + ky)) * 19 + (tx + kx)] << 16);
          } else {
            const float* tile = (const float*)smem;
            a = tile[(ic * 18 + (ty + ky)) * 19 + (tx + kx)];
          }
          const float* wp = wrep + (size_t)(ic * 9 + ky * 3 + kx) * COUT + gr * 16;
          #pragma unroll
          for (int j = 0; j < 16; ++j) acc[j] = fmaf(a, wp[j], acc[j]);
        }
      }
    }
    const float* bp = brep + gr * 16;
    size_t obase = pix * (size_t)out_stride + out_choff + gr * 16;
    #pragma unroll
    for (int j = 0; j < 16; ++j) {
      float r = fmaxf(acc[j] + bp[j], 0.f);
      out[obase + j] = f2bf(r);
    }
  }
}

// ---------------- 1x1 conv + folded BN + relu. in: NHWC bf16 stride K.
// FINAL=false: out NHWC bf16 stride COUT. FINAL=true: out NCHW f32.
template<int K, int COUT, bool FINAL>
__global__ __launch_bounds__(256, 1) void conv1x1_bn_relu(
    const u16* __restrict__ in, const float* __restrict__ wrep,
    const float* __restrict__ brep, void* __restrict__ out_)
{
  const int pid = blockIdx.x * 256 + threadIdx.x;
  const uint4* ip = (const uint4*)(in + (size_t)pid * K);
  constexpr int NG = COUT / 16;
  for (int gr = 0; gr < NG; ++gr) {
    float acc[16];
    #pragma unroll
    for (int j = 0; j < 16; ++j) acc[j] = 0.f;
    for (int k0 = 0; k0 < K; k0 += 8) {
      uint4 u = ip[k0 >> 3];
      float a[8] = { bflo(u.x), bfhi(u.x), bflo(u.y), bfhi(u.y),
                     bflo(u.z), bfhi(u.z), bflo(u.w), bfhi(u.w) };
      #pragma unroll
      for (int kk = 0; kk < 8; ++kk) {
        const float* wp = wrep + (size_t)(k0 + kk) * COUT + gr * 16;
        #pragma unroll
        for (int j = 0; j < 16; ++j) acc[j] = fmaf(a[kk], wp[j], acc[j]);
      }
    }
    if constexpr (FINAL) {
      float* outp = (float*)out_;
      int sp = pid & 65535, b = pid >> 16;
      #pragma unroll
      for (int j = 0; j < 16; ++j) {
        float r = fmaxf(acc[j] + brep[gr * 16 + j], 0.f);
        outp[((size_t)(b * COUT + gr * 16 + j) << 16) + sp] = r;
      }
    } else {
      u16* outp = (u16*)out_;
      #pragma unroll
      for (int j = 0; j < 16; ++j) {
        float r = fmaxf(acc[j] + brep[gr * 16 + j], 0.f);
        outp[(size_t)pid * COUT + gr * 16 + j] = f2bf(r);
      }
    }
  }
}

extern "C" void kernel_launch(void* const* d_in, const int* in_sizes, int n_in,
                              void* d_out, int out_size, void* d_ws, size_t ws_size,
                              hipStream_t stream)
{
  const float* x   = (const float*)d_in[0];
  const float* cw1 = (const float*)d_in[1];
  const float* cb1 = (const float*)d_in[2];
  const float* cw2 = (const float*)d_in[3];
  const float* cb2 = (const float*)d_in[4];
  const float* lw1 = (const float*)d_in[5];
  const float* lb1 = (const float*)d_in[6];
  const float* lg1 = (const float*)d_in[7];
  const float* lbe1= (const float*)d_in[8];
  const float* lm1 = (const float*)d_in[9];
  const float* lv1 = (const float*)d_in[10];
  const float* lw2 = (const float*)d_in[11];
  const float* lb2 = (const float*)d_in[12];
  const float* lg2 = (const float*)d_in[13];
  const float* lbe2= (const float*)d_in[14];
  const float* lm2 = (const float*)d_in[15];
  const float* lv2 = (const float*)d_in[16];
  const float* hw1 = (const float*)d_in[17];
  const float* hb1 = (const float*)d_in[18];
  const float* hg1 = (const float*)d_in[19];
  const float* hbe1= (const float*)d_in[20];
  const float* hm1 = (const float*)d_in[21];
  const float* hv1 = (const float*)d_in[22];
  const float* hw2 = (const float*)d_in[23];
  const float* hb2 = (const float*)d_in[24];
  const float* hg2 = (const float*)d_in[25];
  const float* hbe2= (const float*)d_in[26];
  const float* hm2 = (const float*)d_in[27];
  const float* hv2 = (const float*)d_in[28];
  const float* fw1 = (const float*)d_in[29];
  const float* fb1 = (const float*)d_in[30];
  const float* fg1 = (const float*)d_in[31];
  const float* fbe1= (const float*)d_in[32];
  const float* fm1 = (const float*)d_in[33];
  const float* fv1 = (const float*)d_in[34];
  const float* fw2 = (const float*)d_in[35];
  const float* fb2 = (const float*)d_in[36];
  const float* fg2 = (const float*)d_in[37];
  const float* fbe2= (const float*)d_in[38];
  const float* fm2 = (const float*)d_in[39];
  const float* fv2 = (const float*)d_in[40];

  // ---- workspace layout with lifetime aliasing (peak 805 MB) ----
  // [0]           lf1   134 MB   (live: lconv1 .. lconv2)
  // [134M]        hf1   134 MB   (live: hconv1 .. hconv2)
  // [268M]        region A 537 MB:
  //                 low (12.6M) + high (37.7M)  (live: front .. hconv1)
  //                 fcat (537M)                 (live: lconv2 .. fconv1)
  // f1 (268 MB) aliases lf1+hf1 (dead by fconv1).
  // weights at tail of region A's far end (tiny, after fcat).
  char* ws = (char*)d_ws;
  const size_t MB = 1024 * 1024;
  u16*   lf1  = (u16*)(ws);
  u16*   hf1  = (u16*)(ws + 135 * MB);
  char*  regA = ws + 270 * MB;
  float* low  = (float*)(regA);
  float* high = (float*)(regA + 13 * MB);
  u16*   fcat = (u16*)(regA);                 // overlays low/high after they die
  u16*   f1   = (u16*)(ws);                   // overlays lf1+hf1 after they die
  char*  wtail = regA + 538 * MB;
  size_t woff = 0;
  auto alloc = [&](size_t bytes) -> void* {
    void* p = wtail + woff;
    woff = (woff + bytes + 255) & ~(size_t)255;
    return p;
  };
  float* wl1r = (float*)alloc(27*64*4);    float* bl1r = (float*)alloc(64*4);
  float* wl2r = (float*)alloc(576*128*4);  float* bl2r = (float*)alloc(128*4);
  float* wh1r = (float*)alloc(81*64*4);    float* bh1r = (float*)alloc(64*4);
  float* wh2r = (float*)alloc(576*128*4);  float* bh2r = (float*)alloc(128*4);
  float* wf1r = (float*)alloc(256*128*4);  float* bf1r = (float*)alloc(128*4);
  float* wf2r = (float*)alloc(128*64*4);   float* bf2r = (float*)alloc(64*4);

  // ---- weight repacks (BN folded)
  repack_kernel<<<(27*64+255)/256,  256, 0, stream>>>(lw1, lb1, lg1, lbe1, lm1, lv1, wl1r, bl1r, 27, 64);
  repack_kernel<<<(576*128+255)/256,256, 0, stream>>>(lw2, lb2, lg2, lbe2, lm2, lv2, wl2r, bl2r, 576, 128);
  repack_kernel<<<(81*64+255)/256,  256, 0, stream>>>(hw1, hb1, hg1, hbe1, hm1, hv1, wh1r, bh1r, 81, 64);
  repack_kernel<<<(576*128+255)/256,256, 0, stream>>>(hw2, hb2, hg2, hbe2, hm2, hv2, wh2r, bh2r, 576, 128);
  repack_kernel<<<(256*128+255)/256,256, 0, stream>>>(fw1, fb1, fg1, fbe1, fm1, fv1, wf1r, bf1r, 256, 128);
  repack_kernel<<<(128*64+255)/256, 256, 0, stream>>>(fw2, fb2, fg2, fbe2, fm2, fv2, wf2r, bf2r, 128, 64);

  // ---- front: x -> low, high
  front_kernel<<<4096, 256, 0, stream>>>(x, cw1, cb1, cw2, cb2, low, high);

  // ---- branch convs (order matters for aliasing: both conv1s before conv2s)
  dim3 cgrid(16, 16, 16);
  conv3x3_bn_relu<3, 64, false><<<cgrid, 256, 0, stream>>>(low,  wl1r, bl1r, lf1,  64, 0);
  conv3x3_bn_relu<9, 64, false><<<cgrid, 256, 0, stream>>>(high, wh1r, bh1r, hf1,  64, 0);
  conv3x3_bn_relu<64, 128, true><<<cgrid, 256, 0, stream>>>(lf1, wl2r, bl2r, fcat, 256, 0);
  conv3x3_bn_relu<64, 128, true><<<cgrid, 256, 0, stream>>>(hf1, wh2r, bh2r, fcat, 256, 128);

  // ---- fuse convs
  conv1x1_bn_relu<256, 128, false><<<4096, 256, 0, stream>>>(fcat, wf1r, bf1r, f1);
  conv1x1_bn_relu<128, 64,  true ><<<4096, 256, 0, stream>>>(f1,   wf2r, bf2r, d_out);
}

// Round 3
// 1517.376 us; speedup vs baseline: 6.8555x; 6.8555x over previous
//
#include <hip/hip_runtime.h>
#include <hip/hip_bf16.h>

// FrequencyInflammationDetector — round 3: MFMA (bf16 16x16x32) GEMM for the
// four big convs (fconv1/fconv2 1x1, lconv2/hconv2 3x3 implicit-GEMM).
// Round-2 profile: conv1x1 was 4.25ms with 15.6GB HBM fetch (20x over-fetch,
// L1/L2 thrash from NG-loop re-reads). MFMA kernel reads A once per k-step
// via LDS, weights fragment-prepacked, fp32 accum, fused BN+relu epilogue.

#define EPS_BN 1e-5f

typedef unsigned int u32;
typedef unsigned short u16;
typedef __attribute__((ext_vector_type(8))) short short8;
typedef __attribute__((ext_vector_type(4))) float f32x4;

__device__ __forceinline__ float bflo(u32 u) { return __uint_as_float(u << 16); }
__device__ __forceinline__ float bfhi(u32 u) { return __uint_as_float(u & 0xffff0000u); }
__device__ __forceinline__ u16 f2bf(float f) {
  u32 u = __float_as_uint(f);
  u32 r = (u + 0x7fffu + ((u >> 16) & 1u)) >> 16;   // RNE
  return (u16)r;
}

// ---------------- repack (fp32 [k][oc], BN folded) for the small conv1s
__global__ __launch_bounds__(256) void repack_kernel(
    const float* __restrict__ w, const float* __restrict__ bias,
    const float* __restrict__ g, const float* __restrict__ be,
    const float* __restrict__ m, const float* __restrict__ v,
    float* __restrict__ wrep, float* __restrict__ brep, int K, int COUT)
{
  int idx = blockIdx.x * 256 + threadIdx.x;
  if (idx < K * COUT) {
    int oc = idx % COUT;
    int k  = idx / COUT;
    float alpha = g[oc] * rsqrtf(v[oc] + EPS_BN);
    wrep[idx] = w[(size_t)oc * K + k] * alpha;
  }
  if (idx < COUT) {
    float alpha = g[idx] * rsqrtf(v[idx] + EPS_BN);
    brep[idx] = fmaf(bias[idx], alpha, be[idx] - m[idx] * alpha);
  }
}

// ---------------- repack to MFMA fragment layout (bf16, BN folded)
// k order: k = (ky*KHW+kx)*CIN + ic. record (ks, c, oc) holds 8 bf16:
// wpk[((ks*4+c)*COUT + oc)*8 + e] = W[k = ks*32 + c*8 + e][oc] * alpha
__global__ __launch_bounds__(256) void repack_pack_kernel(
    const float* __restrict__ w, const float* __restrict__ bias,
    const float* __restrict__ g, const float* __restrict__ be,
    const float* __restrict__ m, const float* __restrict__ v,
    u16* __restrict__ wpk, float* __restrict__ brep,
    int CIN, int KHW, int COUT)
{
  int idx = blockIdx.x * 256 + threadIdx.x;
  int K = CIN * KHW * KHW;
  if (idx < K * COUT) {
    int oc = idx % COUT;
    int k  = idx / COUT;
    int ic = k % CIN;
    int kidx = k / CIN;
    int ky = kidx / KHW, kx = kidx % KHW;
    float alpha = g[oc] * rsqrtf(v[oc] + EPS_BN);
    float val = w[(((size_t)oc * CIN + ic) * KHW + ky) * KHW + kx] * alpha;
    int ks = k >> 5, c = (k >> 3) & 3, e = k & 7;
    wpk[((size_t)((ks * 4 + c) * COUT + oc)) * 8 + e] = f2bf(val);
  }
  if (idx < COUT) {
    float alpha = g[idx] * rsqrtf(v[idx] + EPS_BN);
    brep[idx] = fmaf(bias[idx], alpha, be[idx] - m[idx] * alpha);
  }
}

// ---------------- front: 1x1 conv -> relu -> 1x1 conv -> haar DWT
__global__ __launch_bounds__(256) void front_kernel(
    const float* __restrict__ x,
    const float* __restrict__ cw1, const float* __restrict__ cb1,
    const float* __restrict__ cw2, const float* __restrict__ cb2,
    float* __restrict__ low, float* __restrict__ high)
{
  const int pid = blockIdx.x * 256 + threadIdx.x;   // 0 .. 16*256*256-1
  const int wo = pid & 255, ho = (pid >> 8) & 255, b = pid >> 16;
  float hsv[2][2][3];
  #pragma unroll
  for (int dy = 0; dy < 2; ++dy) {
    #pragma unroll
    for (int dx = 0; dx < 2; ++dx) {
      int h = 2 * ho + dy, w = 2 * wo + dx;
      size_t base = ((size_t)(b * 3) << 18) + (size_t)h * 512 + w;
      float p0 = x[base];
      float p1 = x[base + (1u << 18)];
      float p2 = x[base + (2u << 18)];
      float o0 = cb2[0], o1 = cb2[1], o2 = cb2[2];
      #pragma unroll
      for (int o = 0; o < 16; ++o) {
        float t = fmaf(cw1[o*3+2], p2, fmaf(cw1[o*3+1], p1, fmaf(cw1[o*3+0], p0, cb1[o])));
        t = fmaxf(t, 0.f);
        o0 = fmaf(cw2[o],      t, o0);
        o1 = fmaf(cw2[16 + o], t, o1);
        o2 = fmaf(cw2[32 + o], t, o2);
      }
      hsv[dy][dx][0] = o0; hsv[dy][dx][1] = o1; hsv[dy][dx][2] = o2;
    }
  }
  size_t lb = (size_t)pid * 3;
  size_t hb = (size_t)pid * 9;
  #pragma unroll
  for (int c = 0; c < 3; ++c) {
    float a  = hsv[0][0][c], bb = hsv[0][1][c];
    float cc = hsv[1][0][c], dd = hsv[1][1][c];
    low [lb + c]         = (a + bb + cc + dd) * 0.5f;
    high[hb + c*3 + 0]   = (a + bb - cc - dd) * 0.5f;
    high[hb + c*3 + 1]   = (a - bb + cc - dd) * 0.5f;
    high[hb + c*3 + 2]   = (a - bb - cc + dd) * 0.5f;
  }
}

// ---------------- small 3x3 conv + BN + relu (fp32 VALU) for CIN=3/9
template<int CIN, int COUT>
__global__ __launch_bounds__(256, 1) void conv3x3_bn_relu(
    const float* __restrict__ in_, const float* __restrict__ wrep,
    const float* __restrict__ brep, u16* __restrict__ out, int out_stride)
{
  __shared__ __align__(16) float tile[CIN * 18 * 19];
  const int tid = threadIdx.x;
  const int tx = tid & 15, ty = tid >> 4;
  const int w0 = blockIdx.x * 16, h0 = blockIdx.y * 16, b = blockIdx.z;

  for (int idx = tid; idx < 18 * 18 * CIN; idx += 256) {
    int ic = idx % CIN;
    int t  = idx / CIN;
    int x  = t % 18, y = t / 18;
    int gy = h0 + y - 1, gx = w0 + x - 1;
    bool ok = (gy >= 0 && gy < 256 && gx >= 0 && gx < 256);
    size_t gaddr = (size_t)((b * 256 + gy) * 256 + gx) * CIN + ic;
    tile[(ic * 18 + y) * 19 + x] = ok ? in_[gaddr] : 0.f;
  }
  __syncthreads();

  const size_t pix = (size_t)((b * 256 + (h0 + ty)) * 256 + (w0 + tx));
  constexpr int NG = COUT / 16;
  for (int gr = 0; gr < NG; ++gr) {
    float acc[16];
    #pragma unroll
    for (int j = 0; j < 16; ++j) acc[j] = 0.f;
    for (int ic = 0; ic < CIN; ++ic) {
      #pragma unroll
      for (int ky = 0; ky < 3; ++ky) {
        #pragma unroll
        for (int kx = 0; kx < 3; ++kx) {
          float a = tile[(ic * 18 + (ty + ky)) * 19 + (tx + kx)];
          const float* wp = wrep + (size_t)(ic * 9 + ky * 3 + kx) * COUT + gr * 16;
          #pragma unroll
          for (int j = 0; j < 16; ++j) acc[j] = fmaf(a, wp[j], acc[j]);
        }
      }
    }
    const float* bp = brep + gr * 16;
    size_t obase = pix * (size_t)out_stride + gr * 16;
    #pragma unroll
    for (int j = 0; j < 16; ++j) {
      float r = fmaxf(acc[j] + bp[j], 0.f);
      out[obase + j] = f2bf(r);
    }
  }
}

// ---------------- MFMA implicit-GEMM conv (1x1 or 3x3), NHWC bf16 in.
// Block: 128 pixels (half image row) x COUT. 4 waves.
// COUT=128: 2x2 waves, wave tile 64pix x 64oc (MF=4,NF=4)
// COUT=64 : 4x1 waves, wave tile 32pix x 64oc (MF=2,NF=4)
// A-tile LDS chunk layout: A_ld[c][p] = 8 bf16 (k = c*8..c*8+7) of pixel p.
// FINAL=false: out bf16 NHWC (stride/choff). FINAL=true: out f32 NCHW via LDS transpose.
template<int CIN, int KHW, int COUT, bool FINAL>
__global__ __launch_bounds__(256) void mgemm_conv(
    const u16* __restrict__ in, const u16* __restrict__ wpk,
    const float* __restrict__ brep, void* __restrict__ out_,
    int out_stride, int out_choff)
{
  constexpr int K = CIN * KHW * KHW;
  constexpr int KSTEPS = K / 32;
  constexpr int CSL = CIN / 32;                 // 32-wide c-slices per kidx
  constexpr int MF = (COUT == 128) ? 4 : 2;
  constexpr int NF = 4;

  __shared__ uint4 A_ld[4][128];
  __shared__ float sout[FINAL ? 64 : 1][FINAL ? 132 : 1];

  const int tid = threadIdx.x;
  const int l   = tid & 63;
  const int wid = tid >> 6;
  const int h = blockIdx.y, b = blockIdx.z;
  const int w0 = blockIdx.x * 128;

  const int waveM = (COUT == 128) ? (wid >> 1) : wid;
  const int waveN = (COUT == 128) ? (wid & 1) : 0;
  const int pixW  = waveM * ((COUT == 128) ? 64 : 32);
  const int n0    = waveN * 64;

  const int lr = l & 15;    // frag row (pixel) for A, frag col (oc) for B/D
  const int lc = l >> 4;    // k-chunk for A/B, row-group for D

  f32x4 acc[MF][NF];
  #pragma unroll
  for (int m = 0; m < MF; ++m)
    #pragma unroll
    for (int n = 0; n < NF; ++n)
      #pragma unroll
      for (int j = 0; j < 4; ++j) acc[m][n][j] = 0.f;

  const int sp = tid & 127;          // staging pixel
  const int cc = tid >> 7;           // staging chunk pair (cc, cc+2)
  const short8* wpk8 = (const short8*)wpk;

  for (int ks = 0; ks < KSTEPS; ++ks) {
    const int kidx = ks / CSL;
    const int c0   = (ks % CSL) * 32;
    int gy = h, gx = w0 + sp;
    bool ok = true;
    if constexpr (KHW == 3) {
      gy += kidx / 3 - 1;
      gx += kidx % 3 - 1;
      ok = ((unsigned)gy < 256u) && ((unsigned)gx < 256u);
    }
    uint4 v0 = make_uint4(0, 0, 0, 0), v1 = make_uint4(0, 0, 0, 0);
    if (ok) {
      const u16* src = in + (size_t)((b * 256 + gy) * 256 + gx) * CIN + c0 + cc * 8;
      v0 = *(const uint4*)src;
      v1 = *(const uint4*)(src + 16);   // chunk cc+2 (16 u16 = 2 chunks ahead)
    }
    __syncthreads();                    // previous tile's reads complete
    A_ld[cc][sp]     = v0;
    A_ld[cc + 2][sp] = v1;
    __syncthreads();                    // tile ready

    short8 a[MF], bf[NF];
    #pragma unroll
    for (int m = 0; m < MF; ++m)
      a[m] = *(const short8*)&A_ld[lc][pixW + m * 16 + lr];
    #pragma unroll
    for (int n = 0; n < NF; ++n)
      bf[n] = wpk8[(ks * 4 + lc) * COUT + n0 + n * 16 + lr];
    #pragma unroll
    for (int m = 0; m < MF; ++m)
      #pragma unroll
      for (int n = 0; n < NF; ++n)
        acc[m][n] = __builtin_amdgcn_mfma_f32_16x16x32_bf16(a[m], bf[n], acc[m][n], 0, 0, 0);
  }

  // epilogue: bias + relu
  if constexpr (!FINAL) {
    u16* out = (u16*)out_;
    #pragma unroll
    for (int n = 0; n < NF; ++n) {
      const int oc = n0 + n * 16 + lr;
      const float bs = brep[oc];
      #pragma unroll
      for (int m = 0; m < MF; ++m) {
        #pragma unroll
        for (int j = 0; j < 4; ++j) {
          int p = pixW + m * 16 + lc * 4 + j;
          size_t pix = ((size_t)(b * 256 + h)) * 256 + w0 + p;
          float r = fmaxf(acc[m][n][j] + bs, 0.f);
          out[pix * (size_t)out_stride + out_choff + oc] = f2bf(r);
        }
      }
    }
  } else {
    // COUT=64: transpose through LDS, coalesced f32 NCHW stores
    #pragma unroll
    for (int n = 0; n < NF; ++n) {
      const int oc = n * 16 + lr;
      const float bs = brep[oc];
      #pragma unroll
      for (int m = 0; m < MF; ++m) {
        #pragma unroll
        for (int j = 0; j < 4; ++j) {
          int p = pixW + m * 16 + lc * 4 + j;
          sout[oc][p] = fmaxf(acc[m][n][j] + bs, 0.f);
        }
      }
    }
    __syncthreads();
    float* out = (float*)out_;
    for (int i = tid; i < 64 * 128; i += 256) {
      int oc = i >> 7, p = i & 127;
      out[(((size_t)b * 64 + oc) << 16) + (size_t)h * 256 + w0 + p] = sout[oc][p];
    }
  }
}

extern "C" void kernel_launch(void* const* d_in, const int* in_sizes, int n_in,
                              void* d_out, int out_size, void* d_ws, size_t ws_size,
                              hipStream_t stream)
{
  const float* x   = (const float*)d_in[0];
  const float* cw1 = (const float*)d_in[1];
  const float* cb1 = (const float*)d_in[2];
  const float* cw2 = (const float*)d_in[3];
  const float* cb2 = (const float*)d_in[4];
  const float* lw1 = (const float*)d_in[5];
  const float* lb1 = (const float*)d_in[6];
  const float* lg1 = (const float*)d_in[7];
  const float* lbe1= (const float*)d_in[8];
  const float* lm1 = (const float*)d_in[9];
  const float* lv1 = (const float*)d_in[10];
  const float* lw2 = (const float*)d_in[11];
  const float* lb2 = (const float*)d_in[12];
  const float* lg2 = (const float*)d_in[13];
  const float* lbe2= (const float*)d_in[14];
  const float* lm2 = (const float*)d_in[15];
  const float* lv2 = (const float*)d_in[16];
  const float* hw1 = (const float*)d_in[17];
  const float* hb1 = (const float*)d_in[18];
  const float* hg1 = (const float*)d_in[19];
  const float* hbe1= (const float*)d_in[20];
  const float* hm1 = (const float*)d_in[21];
  const float* hv1 = (const float*)d_in[22];
  const float* hw2 = (const float*)d_in[23];
  const float* hb2 = (const float*)d_in[24];
  const float* hg2 = (const float*)d_in[25];
  const float* hbe2= (const float*)d_in[26];
  const float* hm2 = (const float*)d_in[27];
  const float* hv2 = (const float*)d_in[28];
  const float* fw1 = (const float*)d_in[29];
  const float* fb1 = (const float*)d_in[30];
  const float* fg1 = (const float*)d_in[31];
  const float* fbe1= (const float*)d_in[32];
  const float* fm1 = (const float*)d_in[33];
  const float* fv1 = (const float*)d_in[34];
  const float* fw2 = (const float*)d_in[35];
  const float* fb2 = (const float*)d_in[36];
  const float* fg2 = (const float*)d_in[37];
  const float* fbe2= (const float*)d_in[38];
  const float* fm2 = (const float*)d_in[39];
  const float* fv2 = (const float*)d_in[40];

  // ---- workspace layout with lifetime aliasing (peak ~806 MB) ----
  char* ws = (char*)d_ws;
  const size_t MB = 1024 * 1024;
  u16*   lf1  = (u16*)(ws);                   // 134 MB (lconv1..lconv2)
  u16*   hf1  = (u16*)(ws + 135 * MB);        // 134 MB (hconv1..hconv2)
  char*  regA = ws + 270 * MB;
  float* low  = (float*)(regA);               // 12.6 MB (front..lconv1)
  float* high = (float*)(regA + 13 * MB);     // 37.7 MB (front..hconv1)
  u16*   fcat = (u16*)(regA);                 // 537 MB, overlays low/high
  u16*   f1   = (u16*)(ws);                   // 268 MB, overlays lf1+hf1
  char*  wtail = regA + 538 * MB;
  size_t woff = 0;
  auto alloc = [&](size_t bytes) -> void* {
    void* p = wtail + woff;
    woff = (woff + bytes + 255) & ~(size_t)255;
    return p;
  };
  float* wl1r = (float*)alloc(27*64*4);     float* bl1r = (float*)alloc(64*4);
  float* wh1r = (float*)alloc(81*64*4);     float* bh1r = (float*)alloc(64*4);
  u16*   wl2p = (u16*)alloc(576*128*2);     float* bl2r = (float*)alloc(128*4);
  u16*   wh2p = (u16*)alloc(576*128*2);     float* bh2r = (float*)alloc(128*4);
  u16*   wf1p = (u16*)alloc(256*128*2);     float* bf1r = (float*)alloc(128*4);
  u16*   wf2p = (u16*)alloc(128*64*2);      float* bf2r = (float*)alloc(64*4);

  // ---- weight repacks (BN folded)
  repack_kernel<<<(27*64+255)/256, 256, 0, stream>>>(lw1, lb1, lg1, lbe1, lm1, lv1, wl1r, bl1r, 27, 64);
  repack_kernel<<<(81*64+255)/256, 256, 0, stream>>>(hw1, hb1, hg1, hbe1, hm1, hv1, wh1r, bh1r, 81, 64);
  repack_pack_kernel<<<(576*128+255)/256, 256, 0, stream>>>(lw2, lb2, lg2, lbe2, lm2, lv2, wl2p, bl2r, 64, 3, 128);
  repack_pack_kernel<<<(576*128+255)/256, 256, 0, stream>>>(hw2, hb2, hg2, hbe2, hm2, hv2, wh2p, bh2r, 64, 3, 128);
  repack_pack_kernel<<<(256*128+255)/256, 256, 0, stream>>>(fw1, fb1, fg1, fbe1, fm1, fv1, wf1p, bf1r, 256, 1, 128);
  repack_pack_kernel<<<(128*64+255)/256,  256, 0, stream>>>(fw2, fb2, fg2, fbe2, fm2, fv2, wf2p, bf2r, 128, 1, 64);

  // ---- front: x -> low, high
  front_kernel<<<4096, 256, 0, stream>>>(x, cw1, cb1, cw2, cb2, low, high);

  // ---- small branch convs (fp32 VALU)
  dim3 cgrid(16, 16, 16);
  conv3x3_bn_relu<3, 64><<<cgrid, 256, 0, stream>>>(low,  wl1r, bl1r, lf1, 64);
  conv3x3_bn_relu<9, 64><<<cgrid, 256, 0, stream>>>(high, wh1r, bh1r, hf1, 64);

  // ---- big convs: MFMA implicit GEMM
  dim3 ggrid(2, 256, 16);
  mgemm_conv<64, 3, 128, false><<<ggrid, 256, 0, stream>>>(lf1, wl2p, bl2r, fcat, 256, 0);
  mgemm_conv<64, 3, 128, false><<<ggrid, 256, 0, stream>>>(hf1, wh2p, bh2r, fcat, 256, 128);
  mgemm_conv<256, 1, 128, false><<<ggrid, 256, 0, stream>>>(fcat, wf1p, bf1r, f1, 128, 0);
  mgemm_conv<128, 1, 64, true><<<ggrid, 256, 0, stream>>>(f1, wf2p, bf2r, d_out, 0, 0);
}

// Round 4
// 1192.734 us; speedup vs baseline: 8.7215x; 1.2722x over previous
//
#include <hip/hip_runtime.h>
#include <hip/hip_bf16.h>

// FrequencyInflammationDetector — round 4.
// R3 profile: 3x3 mgemm 350us each with MfmaUtil/VALU/HBM all ~18%, Occ 23%
// -> barrier-bound (36 barriers/block, vmcnt0 drain each K-step).
// Fixes: (1) conv3x3_mfma stages 3 halo rows ONCE (50KB LDS), K-loop is
// barrier-free ds_read+MFMA; XCD-swizzled grid for halo L2 reuse.
// (2) fconv1+fconv2 fused: f1 tile lives in LDS (saves 537MB HBM round-trip).
// (3) LDS-repacked epilogues -> dwordx4 stores.

#define EPS_BN 1e-5f

typedef unsigned int u32;
typedef unsigned short u16;
typedef __attribute__((ext_vector_type(8))) short short8;
typedef __attribute__((ext_vector_type(4))) float f32x4;

__device__ __forceinline__ u16 f2bf(float f) {
  u32 u = __float_as_uint(f);
  u32 r = (u + 0x7fffu + ((u >> 16) & 1u)) >> 16;   // RNE
  return (u16)r;
}

// ---------------- repack (fp32 [k][oc], BN folded) for the small conv1s
__global__ __launch_bounds__(256) void repack_kernel(
    const float* __restrict__ w, const float* __restrict__ bias,
    const float* __restrict__ g, const float* __restrict__ be,
    const float* __restrict__ m, const float* __restrict__ v,
    float* __restrict__ wrep, float* __restrict__ brep, int K, int COUT)
{
  int idx = blockIdx.x * 256 + threadIdx.x;
  if (idx < K * COUT) {
    int oc = idx % COUT;
    int k  = idx / COUT;
    float alpha = g[oc] * rsqrtf(v[oc] + EPS_BN);
    wrep[idx] = w[(size_t)oc * K + k] * alpha;
  }
  if (idx < COUT) {
    float alpha = g[idx] * rsqrtf(v[idx] + EPS_BN);
    brep[idx] = fmaf(bias[idx], alpha, be[idx] - m[idx] * alpha);
  }
}

// ---------------- repack to MFMA fragment layout (bf16, BN folded)
// k = (ky*KHW+kx)*CIN + ic ; wpk[((ks*4+c)*COUT + oc)*8 + e] = W[k=ks*32+c*8+e][oc]*alpha
__global__ __launch_bounds__(256) void repack_pack_kernel(
    const float* __restrict__ w, const float* __restrict__ bias,
    const float* __restrict__ g, const float* __restrict__ be,
    const float* __restrict__ m, const float* __restrict__ v,
    u16* __restrict__ wpk, float* __restrict__ brep,
    int CIN, int KHW, int COUT)
{
  int idx = blockIdx.x * 256 + threadIdx.x;
  int K = CIN * KHW * KHW;
  if (idx < K * COUT) {
    int oc = idx % COUT;
    int k  = idx / COUT;
    int ic = k % CIN;
    int kidx = k / CIN;
    int ky = kidx / KHW, kx = kidx % KHW;
    float alpha = g[oc] * rsqrtf(v[oc] + EPS_BN);
    float val = w[(((size_t)oc * CIN + ic) * KHW + ky) * KHW + kx] * alpha;
    int ks = k >> 5, c = (k >> 3) & 3, e = k & 7;
    wpk[((size_t)((ks * 4 + c) * COUT + oc)) * 8 + e] = f2bf(val);
  }
  if (idx < COUT) {
    float alpha = g[idx] * rsqrtf(v[idx] + EPS_BN);
    brep[idx] = fmaf(bias[idx], alpha, be[idx] - m[idx] * alpha);
  }
}

// ---------------- front: 1x1 conv -> relu -> 1x1 conv -> haar DWT
__global__ __launch_bounds__(256) void front_kernel(
    const float* __restrict__ x,
    const float* __restrict__ cw1, const float* __restrict__ cb1,
    const float* __restrict__ cw2, const float* __restrict__ cb2,
    float* __restrict__ low, float* __restrict__ high)
{
  const int pid = blockIdx.x * 256 + threadIdx.x;
  const int wo = pid & 255, ho = (pid >> 8) & 255, b = pid >> 16;
  float hsv[2][2][3];
  #pragma unroll
  for (int dy = 0; dy < 2; ++dy) {
    #pragma unroll
    for (int dx = 0; dx < 2; ++dx) {
      int h = 2 * ho + dy, w = 2 * wo + dx;
      size_t base = ((size_t)(b * 3) << 18) + (size_t)h * 512 + w;
      float p0 = x[base];
      float p1 = x[base + (1u << 18)];
      float p2 = x[base + (2u << 18)];
      float o0 = cb2[0], o1 = cb2[1], o2 = cb2[2];
      #pragma unroll
      for (int o = 0; o < 16; ++o) {
        float t = fmaf(cw1[o*3+2], p2, fmaf(cw1[o*3+1], p1, fmaf(cw1[o*3+0], p0, cb1[o])));
        t = fmaxf(t, 0.f);
        o0 = fmaf(cw2[o],      t, o0);
        o1 = fmaf(cw2[16 + o], t, o1);
        o2 = fmaf(cw2[32 + o], t, o2);
      }
      hsv[dy][dx][0] = o0; hsv[dy][dx][1] = o1; hsv[dy][dx][2] = o2;
    }
  }
  size_t lb = (size_t)pid * 3;
  size_t hb = (size_t)pid * 9;
  #pragma unroll
  for (int c = 0; c < 3; ++c) {
    float a  = hsv[0][0][c], bb = hsv[0][1][c];
    float cc = hsv[1][0][c], dd = hsv[1][1][c];
    low [lb + c]         = (a + bb + cc + dd) * 0.5f;
    high[hb + c*3 + 0]   = (a + bb - cc - dd) * 0.5f;
    high[hb + c*3 + 1]   = (a - bb + cc - dd) * 0.5f;
    high[hb + c*3 + 2]   = (a - bb - cc + dd) * 0.5f;
  }
}

// ---------------- small 3x3 conv + BN + relu (fp32 VALU) for CIN=3/9
template<int CIN, int COUT>
__global__ __launch_bounds__(256, 1) void conv3x3_bn_relu(
    const float* __restrict__ in_, const float* __restrict__ wrep,
    const float* __restrict__ brep, u16* __restrict__ out, int out_stride)
{
  __shared__ __align__(16) float tile[CIN * 18 * 19];
  const int tid = threadIdx.x;
  const int tx = tid & 15, ty = tid >> 4;
  const int w0 = blockIdx.x * 16, h0 = blockIdx.y * 16, b = blockIdx.z;

  for (int idx = tid; idx < 18 * 18 * CIN; idx += 256) {
    int ic = idx % CIN;
    int t  = idx / CIN;
    int x  = t % 18, y = t / 18;
    int gy = h0 + y - 1, gx = w0 + x - 1;
    bool ok = (gy >= 0 && gy < 256 && gx >= 0 && gx < 256);
    size_t gaddr = (size_t)((b * 256 + gy) * 256 + gx) * CIN + ic;
    tile[(ic * 18 + y) * 19 + x] = ok ? in_[gaddr] : 0.f;
  }
  __syncthreads();

  const size_t pix = (size_t)((b * 256 + (h0 + ty)) * 256 + (w0 + tx));
  constexpr int NG = COUT / 16;
  for (int gr = 0; gr < NG; ++gr) {
    float acc[16];
    #pragma unroll
    for (int j = 0; j < 16; ++j) acc[j] = 0.f;
    for (int ic = 0; ic < CIN; ++ic) {
      #pragma unroll
      for (int ky = 0; ky < 3; ++ky) {
        #pragma unroll
        for (int kx = 0; kx < 3; ++kx) {
          float a = tile[(ic * 18 + (ty + ky)) * 19 + (tx + kx)];
          const float* wp = wrep + (size_t)(ic * 9 + ky * 3 + kx) * COUT + gr * 16;
          #pragma unroll
          for (int j = 0; j < 16; ++j) acc[j] = fmaf(a, wp[j], acc[j]);
        }
      }
    }
    const float* bp = brep + gr * 16;
    size_t obase = pix * (size_t)out_stride + gr * 16;
    #pragma unroll
    for (int j = 0; j < 16; ++j) {
      float r = fmaxf(acc[j] + bp[j], 0.f);
      out[obase + j] = f2bf(r);
    }
  }
}

// ---------------- 3x3 conv, CIN=64, COUT=128, MFMA, halo-row LDS staging.
// Block = 128 px (half row) x 128 oc, 4 waves (2M x 2N), wave 64px x 64oc.
// Stage rows h-1..h+1 x 130 px x 64ch ONCE; K-loop (18 steps) barrier-free.
// XCD-swizzled 1-D grid (8192 blocks) for halo L2 locality.
__global__ __launch_bounds__(256, 2) void conv3x3_mfma(
    const u16* __restrict__ in, const u16* __restrict__ wpk,
    const float* __restrict__ brep, u16* __restrict__ out,
    int out_stride, int out_choff)
{
  __shared__ __align__(16) unsigned char smem[3 * 8 * 132 * 16];   // 50688 B
  uint4 (*Arow)[8][132] = (uint4(*)[8][132])smem;

  const int tid = threadIdx.x;
  const int l = tid & 63, wid = tid >> 6;
  const int bid = blockIdx.x;
  const int swz = (bid & 7) * 1024 + (bid >> 3);   // 8192 % 8 == 0 -> bijective
  const int xh = swz & 1, h = (swz >> 1) & 255, b = swz >> 9;
  const int w0 = xh * 128;

  const int waveM = wid >> 1, waveN = wid & 1;
  const int pixW = waveM * 64, n0 = waveN * 64;
  const int lr = l & 15, lc = l >> 4;

  // stage: 3 rows x 130 px x 8 chunks (chunk fastest -> coalesced global reads)
  for (int i = tid; i < 3 * 130 * 8; i += 256) {
    int c = i & 7;
    int t = i >> 3;
    int px = t % 130;
    int row = t / 130;
    int gy = h + row - 1, gx = w0 + px - 1;
    uint4 vv = make_uint4(0, 0, 0, 0);
    if ((unsigned)gy < 256u && (unsigned)gx < 256u)
      vv = *(const uint4*)(in + ((size_t)((b * 256 + gy) * 256 + gx)) * 64 + c * 8);
    Arow[row][c][px] = vv;
  }
  __syncthreads();

  f32x4 acc[4][4];
  #pragma unroll
  for (int m = 0; m < 4; ++m)
    #pragma unroll
    for (int n = 0; n < 4; ++n)
      #pragma unroll
      for (int j = 0; j < 4; ++j) acc[m][n][j] = 0.f;

  const short8* wpk8 = (const short8*)wpk;
  #pragma unroll
  for (int kidx = 0; kidx < 9; ++kidx) {
    const int ky = kidx / 3, kx = kidx % 3;
    #pragma unroll
    for (int cs = 0; cs < 2; ++cs) {
      short8 a[4], bf[4];
      #pragma unroll
      for (int m = 0; m < 4; ++m)
        a[m] = *(const short8*)&Arow[ky][cs * 4 + lc][pixW + m * 16 + lr + kx];
      #pragma unroll
      for (int n = 0; n < 4; ++n)
        bf[n] = wpk8[((kidx * 2 + cs) * 4 + lc) * 128 + n0 + n * 16 + lr];
      #pragma unroll
      for (int m = 0; m < 4; ++m)
        #pragma unroll
        for (int n = 0; n < 4; ++n)
          acc[m][n] = __builtin_amdgcn_mfma_f32_16x16x32_bf16(a[m], bf[n], acc[m][n], 0, 0, 0);
    }
  }

  // epilogue: bias+relu -> LDS u16 [128px][136] -> dwordx4 stores
  __syncthreads();
  u16 (*soutp)[136] = (u16(*)[136])smem;
  #pragma unroll
  for (int n = 0; n < 4; ++n) {
    const int oc = n0 + n * 16 + lr;
    const float bs = brep[oc];
    #pragma unroll
    for (int m = 0; m < 4; ++m)
      #pragma unroll
      for (int j = 0; j < 4; ++j)
        soutp[pixW + m * 16 + lc * 4 + j][oc] = f2bf(fmaxf(acc[m][n][j] + bs, 0.f));
  }
  __syncthreads();
  const size_t rowbase = (size_t)((b * 256 + h) * 256 + w0);
  for (int i = tid; i < 128 * 16; i += 256) {
    int c = i & 15, px = i >> 4;
    *(uint4*)(out + (rowbase + px) * (size_t)out_stride + out_choff + c * 8) =
        *(const uint4*)&soutp[px][c * 8];
  }
}

// ---------------- fused fconv1(256->128) + fconv2(128->64) via LDS f1 tile.
// Block = 128 px, 4 waves. Stage1: wave 64px x 64oc (2Mx2N). f1 tile -> LDS.
// Stage2: wave 64px x 32oc, K=128 from LDS. Out: NCHW f32 via LDS transpose.
__global__ __launch_bounds__(256) void fuse_mfma(
    const u16* __restrict__ fcat,
    const u16* __restrict__ w1p, const float* __restrict__ b1r,
    const u16* __restrict__ w2p, const float* __restrict__ b2r,
    float* __restrict__ out)
{
  __shared__ __align__(16) unsigned char smem[8192 + 16 * 128 * 16]; // A_ld + A2 = 40960
  uint4 (*A_ld)[128] = (uint4(*)[128])smem;
  uint4 (*A2)[128]   = (uint4(*)[128])(smem + 8192);
  float (*sout)[132] = (float(*)[132])smem;      // alias (33792 <= 40960)

  const int tid = threadIdx.x;
  const int l = tid & 63, wid = tid >> 6;
  const int w0 = blockIdx.x * 128, hh = blockIdx.y, b = blockIdx.z;
  const int waveM = wid >> 1, waveN = wid & 1;
  const int pixW = waveM * 64, n0 = waveN * 64;
  const int lr = l & 15, lc = l >> 4;
  const int sp = tid & 127, cc = tid >> 7;
  const size_t rowbase = (size_t)((b * 256 + hh) * 256 + w0);

  f32x4 acc[4][4];
  #pragma unroll
  for (int m = 0; m < 4; ++m)
    #pragma unroll
    for (int n = 0; n < 4; ++n)
      #pragma unroll
      for (int j = 0; j < 4; ++j) acc[m][n][j] = 0.f;

  const short8* w1p8 = (const short8*)w1p;
  for (int ks = 0; ks < 8; ++ks) {
    const u16* src = fcat + (rowbase + sp) * 256 + ks * 32 + cc * 8;
    uint4 v0 = *(const uint4*)src;
    uint4 v1 = *(const uint4*)(src + 16);
    __syncthreads();
    A_ld[cc][sp] = v0;
    A_ld[cc + 2][sp] = v1;
    __syncthreads();
    short8 a[4], bf[4];
    #pragma unroll
    for (int m = 0; m < 4; ++m)
      a[m] = *(const short8*)&A_ld[lc][pixW + m * 16 + lr];
    #pragma unroll
    for (int n = 0; n < 4; ++n)
      bf[n] = w1p8[(ks * 4 + lc) * 128 + n0 + n * 16 + lr];
    #pragma unroll
    for (int m = 0; m < 4; ++m)
      #pragma unroll
      for (int n = 0; n < 4; ++n)
        acc[m][n] = __builtin_amdgcn_mfma_f32_16x16x32_bf16(a[m], bf[n], acc[m][n], 0, 0, 0);
  }

  // stage-1 epilogue -> f1 tile in LDS (chunk layout A2[ch>>3][px], 8 ch/u16x8)
  u16* A2u = (u16*)A2;
  #pragma unroll
  for (int n = 0; n < 4; ++n) {
    const int oc = n0 + n * 16 + lr;
    const float bs = b1r[oc];
    #pragma unroll
    for (int m = 0; m < 4; ++m)
      #pragma unroll
      for (int j = 0; j < 4; ++j) {
        int px = pixW + m * 16 + lc * 4 + j;
        A2u[((size_t)(oc >> 3) * 128 + px) * 8 + (oc & 7)] =
            f2bf(fmaxf(acc[m][n][j] + bs, 0.f));
      }
  }
  __syncthreads();

  // stage 2: K=128 from LDS, wave 64px x 32oc
  const int n02 = waveN * 32;
  f32x4 acc2[4][2];
  #pragma unroll
  for (int m = 0; m < 4; ++m)
    #pragma unroll
    for (int n = 0; n < 2; ++n)
      #pragma unroll
      for (int j = 0; j < 4; ++j) acc2[m][n][j] = 0.f;

  const short8* w2p8 = (const short8*)w2p;
  #pragma unroll
  for (int ks = 0; ks < 4; ++ks) {
    short8 a[4], bf[2];
    #pragma unroll
    for (int m = 0; m < 4; ++m)
      a[m] = *(const short8*)&A2[ks * 4 + lc][pixW + m * 16 + lr];
    #pragma unroll
    for (int n = 0; n < 2; ++n)
      bf[n] = w2p8[(ks * 4 + lc) * 64 + n02 + n * 16 + lr];
    #pragma unroll
    for (int m = 0; m < 4; ++m)
      #pragma unroll
      for (int n = 0; n < 2; ++n)
        acc2[m][n] = __builtin_amdgcn_mfma_f32_16x16x32_bf16(a[m], bf[n], acc2[m][n], 0, 0, 0);
  }
  __syncthreads();      // all A2 reads done before sout alias write

  #pragma unroll
  for (int n = 0; n < 2; ++n) {
    const int oc = n02 + n * 16 + lr;
    const float bs = b2r[oc];
    #pragma unroll
    for (int m = 0; m < 4; ++m)
      #pragma unroll
      for (int j = 0; j < 4; ++j)
        sout[oc][pixW + m * 16 + lc * 4 + j] = fmaxf(acc2[m][n][j] + bs, 0.f);
  }
  __syncthreads();
  for (int i = tid; i < 64 * 128; i += 256) {
    int oc = i >> 7, px = i & 127;
    out[(((size_t)b * 64 + oc) << 16) + (size_t)hh * 256 + w0 + px] = sout[oc][px];
  }
}

extern "C" void kernel_launch(void* const* d_in, const int* in_sizes, int n_in,
                              void* d_out, int out_size, void* d_ws, size_t ws_size,
                              hipStream_t stream)
{
  const float* x   = (const float*)d_in[0];
  const float* cw1 = (const float*)d_in[1];
  const float* cb1 = (const float*)d_in[2];
  const float* cw2 = (const float*)d_in[3];
  const float* cb2 = (const float*)d_in[4];
  const float* lw1 = (const float*)d_in[5];
  const float* lb1 = (const float*)d_in[6];
  const float* lg1 = (const float*)d_in[7];
  const float* lbe1= (const float*)d_in[8];
  const float* lm1 = (const float*)d_in[9];
  const float* lv1 = (const float*)d_in[10];
  const float* lw2 = (const float*)d_in[11];
  const float* lb2 = (const float*)d_in[12];
  const float* lg2 = (const float*)d_in[13];
  const float* lbe2= (const float*)d_in[14];
  const float* lm2 = (const float*)d_in[15];
  const float* lv2 = (const float*)d_in[16];
  const float* hw1 = (const float*)d_in[17];
  const float* hb1 = (const float*)d_in[18];
  const float* hg1 = (const float*)d_in[19];
  const float* hbe1= (const float*)d_in[20];
  const float* hm1 = (const float*)d_in[21];
  const float* hv1 = (const float*)d_in[22];
  const float* hw2 = (const float*)d_in[23];
  const float* hb2 = (const float*)d_in[24];
  const float* hg2 = (const float*)d_in[25];
  const float* hbe2= (const float*)d_in[26];
  const float* hm2 = (const float*)d_in[27];
  const float* hv2 = (const float*)d_in[28];
  const float* fw1 = (const float*)d_in[29];
  const float* fb1 = (const float*)d_in[30];
  const float* fg1 = (const float*)d_in[31];
  const float* fbe1= (const float*)d_in[32];
  const float* fm1 = (const float*)d_in[33];
  const float* fv1 = (const float*)d_in[34];
  const float* fw2 = (const float*)d_in[35];
  const float* fb2 = (const float*)d_in[36];
  const float* fg2 = (const float*)d_in[37];
  const float* fbe2= (const float*)d_in[38];
  const float* fm2 = (const float*)d_in[39];
  const float* fv2 = (const float*)d_in[40];

  // ---- workspace layout with lifetime aliasing (peak ~806 MB) ----
  char* ws = (char*)d_ws;
  const size_t MB = 1024 * 1024;
  u16*   lf1  = (u16*)(ws);                   // 134 MB (lconv1..lconv2)
  u16*   hf1  = (u16*)(ws + 135 * MB);        // 134 MB (hconv1..hconv2)
  char*  regA = ws + 270 * MB;
  float* low  = (float*)(regA);               // 12.6 MB (front..lconv1)
  float* high = (float*)(regA + 13 * MB);     // 37.7 MB (front..hconv1)
  u16*   fcat = (u16*)(regA);                 // 537 MB, overlays low/high
  char*  wtail = regA + 538 * MB;
  size_t woff = 0;
  auto alloc = [&](size_t bytes) -> void* {
    void* p = wtail + woff;
    woff = (woff + bytes + 255) & ~(size_t)255;
    return p;
  };
  float* wl1r = (float*)alloc(27*64*4);     float* bl1r = (float*)alloc(64*4);
  float* wh1r = (float*)alloc(81*64*4);     float* bh1r = (float*)alloc(64*4);
  u16*   wl2p = (u16*)alloc(576*128*2);     float* bl2r = (float*)alloc(128*4);
  u16*   wh2p = (u16*)alloc(576*128*2);     float* bh2r = (float*)alloc(128*4);
  u16*   wf1p = (u16*)alloc(256*128*2);     float* bf1r = (float*)alloc(128*4);
  u16*   wf2p = (u16*)alloc(128*64*2);      float* bf2r = (float*)alloc(64*4);

  // ---- weight repacks (BN folded)
  repack_kernel<<<(27*64+255)/256, 256, 0, stream>>>(lw1, lb1, lg1, lbe1, lm1, lv1, wl1r, bl1r, 27, 64);
  repack_kernel<<<(81*64+255)/256, 256, 0, stream>>>(hw1, hb1, hg1, hbe1, hm1, hv1, wh1r, bh1r, 81, 64);
  repack_pack_kernel<<<(576*128+255)/256, 256, 0, stream>>>(lw2, lb2, lg2, lbe2, lm2, lv2, wl2p, bl2r, 64, 3, 128);
  repack_pack_kernel<<<(576*128+255)/256, 256, 0, stream>>>(hw2, hb2, hg2, hbe2, hm2, hv2, wh2p, bh2r, 64, 3, 128);
  repack_pack_kernel<<<(256*128+255)/256, 256, 0, stream>>>(fw1, fb1, fg1, fbe1, fm1, fv1, wf1p, bf1r, 256, 1, 128);
  repack_pack_kernel<<<(128*64+255)/256,  256, 0, stream>>>(fw2, fb2, fg2, fbe2, fm2, fv2, wf2p, bf2r, 128, 1, 64);

  // ---- front: x -> low, high
  front_kernel<<<4096, 256, 0, stream>>>(x, cw1, cb1, cw2, cb2, low, high);

  // ---- small branch convs (fp32 VALU)
  dim3 cgrid(16, 16, 16);
  conv3x3_bn_relu<3, 64><<<cgrid, 256, 0, stream>>>(low,  wl1r, bl1r, lf1, 64);
  conv3x3_bn_relu<9, 64><<<cgrid, 256, 0, stream>>>(high, wh1r, bh1r, hf1, 64);

  // ---- big 3x3 convs: halo-staged MFMA (1-D XCD-swizzled grid)
  conv3x3_mfma<<<8192, 256, 0, stream>>>(lf1, wl2p, bl2r, fcat, 256, 0);
  conv3x3_mfma<<<8192, 256, 0, stream>>>(hf1, wh2p, bh2r, fcat, 256, 128);

  // ---- fused fuse-stage
  dim3 fgrid(2, 256, 16);
  fuse_mfma<<<fgrid, 256, 0, stream>>>(fcat, wf1p, bf1r, wf2p, bf2r, (float*)d_out);
}

// Round 5
// 1049.626 us; speedup vs baseline: 9.9106x; 1.1363x over previous
//
#include <hip/hip_runtime.h>
#include <hip/hip_bf16.h>

// FrequencyInflammationDetector — round 5.
// R4 profile: conv3x3_mfma 239us, MfmaUtil 27%, SQ_LDS_BANK_CONFLICT 2.0e7
// (4-way conflict on staging writes: chunk stride 132*16B -> bank+16).
// Fixes: (1) pad chunk stride 132->133 (bank+20, conflict-free staging).
// (2) fuse_mfma: stage 64px x 256ch tile ONCE, barrier-free K-loops, LDS alias
// for f1 tile and f32 out tile (16 barriers -> 5).
// (3) branch conv1s -> MFMA (K=160 zero-padded), front emits bf16 ch16-padded.

#define EPS_BN 1e-5f

typedef unsigned int u32;
typedef unsigned short u16;
typedef __attribute__((ext_vector_type(8))) short short8;
typedef __attribute__((ext_vector_type(4))) float f32x4;

__device__ __forceinline__ u16 f2bf(float f) {
  u32 u = __float_as_uint(f);
  u32 r = (u + 0x7fffu + ((u >> 16) & 1u)) >> 16;   // RNE
  return (u16)r;
}

// ---------------- repack to MFMA fragment layout (bf16, BN folded)
// k = (ky*KHW+kx)*CIN + ic ; wpk[((ks*4+c)*COUT + oc)*8 + e] = W[k=ks*32+c*8+e][oc]*alpha
__global__ __launch_bounds__(256) void repack_pack_kernel(
    const float* __restrict__ w, const float* __restrict__ bias,
    const float* __restrict__ g, const float* __restrict__ be,
    const float* __restrict__ m, const float* __restrict__ v,
    u16* __restrict__ wpk, float* __restrict__ brep,
    int CIN, int KHW, int COUT)
{
  int idx = blockIdx.x * 256 + threadIdx.x;
  int K = CIN * KHW * KHW;
  if (idx < K * COUT) {
    int oc = idx % COUT;
    int k  = idx / COUT;
    int ic = k % CIN;
    int kidx = k / CIN;
    int ky = kidx / KHW, kx = kidx % KHW;
    float alpha = g[oc] * rsqrtf(v[oc] + EPS_BN);
    float val = w[(((size_t)oc * CIN + ic) * KHW + ky) * KHW + kx] * alpha;
    int ks = k >> 5, c = (k >> 3) & 3, e = k & 7;
    wpk[((size_t)((ks * 4 + c) * COUT + oc)) * 8 + e] = f2bf(val);
  }
  if (idx < COUT) {
    float alpha = g[idx] * rsqrtf(v[idx] + EPS_BN);
    brep[idx] = fmaf(bias[idx], alpha, be[idx] - m[idx] * alpha);
  }
}

// ---------------- repack for branch conv1: K padded to 160 (kidx 0..9, ic 0..15)
// k = kidx*16 + ic ; kidx<9 && ic<CIN -> real weight, else 0.
__global__ __launch_bounds__(256) void repack_pad_pack_kernel(
    const float* __restrict__ w, const float* __restrict__ bias,
    const float* __restrict__ g, const float* __restrict__ be,
    const float* __restrict__ m, const float* __restrict__ v,
    u16* __restrict__ wpk, float* __restrict__ brep, int CIN, int COUT)
{
  int idx = blockIdx.x * 256 + threadIdx.x;
  if (idx < 160 * COUT) {
    int oc = idx % COUT;
    int k  = idx / COUT;
    int kidx = k >> 4, ic = k & 15;
    float val = 0.f;
    if (kidx < 9 && ic < CIN) {
      int ky = kidx / 3, kx = kidx % 3;
      float alpha = g[oc] * rsqrtf(v[oc] + EPS_BN);
      val = w[(((size_t)oc * CIN + ic) * 3 + ky) * 3 + kx] * alpha;
    }
    int ks = k >> 5, c = (k >> 3) & 3, e = k & 7;
    wpk[((size_t)((ks * 4 + c) * COUT + oc)) * 8 + e] = f2bf(val);
  }
  if (idx < COUT) {
    float alpha = g[idx] * rsqrtf(v[idx] + EPS_BN);
    brep[idx] = fmaf(bias[idx], alpha, be[idx] - m[idx] * alpha);
  }
}

// ---------------- front: 1x1 -> relu -> 1x1 -> haar. Out: bf16 NHWC ch16-padded.
__global__ __launch_bounds__(256) void front_kernel(
    const float* __restrict__ x,
    const float* __restrict__ cw1, const float* __restrict__ cb1,
    const float* __restrict__ cw2, const float* __restrict__ cb2,
    u16* __restrict__ low16, u16* __restrict__ high16)
{
  const int pid = blockIdx.x * 256 + threadIdx.x;
  const int wo = pid & 255, ho = (pid >> 8) & 255, b = pid >> 16;
  float hsv[2][2][3];
  #pragma unroll
  for (int dy = 0; dy < 2; ++dy) {
    #pragma unroll
    for (int dx = 0; dx < 2; ++dx) {
      int h = 2 * ho + dy, w = 2 * wo + dx;
      size_t base = ((size_t)(b * 3) << 18) + (size_t)h * 512 + w;
      float p0 = x[base];
      float p1 = x[base + (1u << 18)];
      float p2 = x[base + (2u << 18)];
      float o0 = cb2[0], o1 = cb2[1], o2 = cb2[2];
      #pragma unroll
      for (int o = 0; o < 16; ++o) {
        float t = fmaf(cw1[o*3+2], p2, fmaf(cw1[o*3+1], p1, fmaf(cw1[o*3+0], p0, cb1[o])));
        t = fmaxf(t, 0.f);
        o0 = fmaf(cw2[o],      t, o0);
        o1 = fmaf(cw2[16 + o], t, o1);
        o2 = fmaf(cw2[32 + o], t, o2);
      }
      hsv[dy][dx][0] = o0; hsv[dy][dx][1] = o1; hsv[dy][dx][2] = o2;
    }
  }
  u16 lrec[16], hrec[16];
  #pragma unroll
  for (int i = 0; i < 16; ++i) { lrec[i] = 0; hrec[i] = 0; }
  #pragma unroll
  for (int c = 0; c < 3; ++c) {
    float a  = hsv[0][0][c], bb = hsv[0][1][c];
    float cc = hsv[1][0][c], dd = hsv[1][1][c];
    lrec[c]         = f2bf((a + bb + cc + dd) * 0.5f);
    hrec[c * 3 + 0] = f2bf((a + bb - cc - dd) * 0.5f);
    hrec[c * 3 + 1] = f2bf((a - bb + cc - dd) * 0.5f);
    hrec[c * 3 + 2] = f2bf((a - bb - cc + dd) * 0.5f);
  }
  *(uint4*)(low16  + (size_t)pid * 16)     = *(const uint4*)&lrec[0];
  *(uint4*)(low16  + (size_t)pid * 16 + 8) = *(const uint4*)&lrec[8];
  *(uint4*)(high16 + (size_t)pid * 16)     = *(const uint4*)&hrec[0];
  *(uint4*)(high16 + (size_t)pid * 16 + 8) = *(const uint4*)&hrec[8];
}

// ---------------- branch conv1 (3x3, CIN<=16 padded, COUT=64), MFMA, halo rows.
// Block = 128px x 64oc, 4 waves (2M x 2N): wave 64px x 32oc. K=160 (5 steps).
__global__ __launch_bounds__(256) void conv3x3s_mfma(
    const u16* __restrict__ in16, const u16* __restrict__ wpk,
    const float* __restrict__ brep, u16* __restrict__ out)
{
  __shared__ __align__(16) u16 smem[3 * 130 * 24];    // 18720 B (epilogue aliases)
  u16 (*Arow)[130][24] = (u16(*)[130][24])smem;

  const int tid = threadIdx.x;
  const int l = tid & 63, wid = tid >> 6;
  const int bid = blockIdx.x;
  const int swz = (bid & 7) * 1024 + (bid >> 3);
  const int xh = swz & 1, h = (swz >> 1) & 255, b = swz >> 9;
  const int w0 = xh * 128;
  const int pixW = (wid >> 1) * 64, n0 = (wid & 1) * 32;
  const int lr = l & 15, lc = l >> 4;

  // stage 3 halo rows x 130 px x 16ch (2 uint4 per record)
  for (int i = tid; i < 3 * 130 * 2; i += 256) {
    int half = i & 1, rec = i >> 1;
    int px = rec % 130, row = rec / 130;
    int gy = h + row - 1, gx = w0 + px - 1;
    uint4 vv = make_uint4(0, 0, 0, 0);
    if ((unsigned)gy < 256u && (unsigned)gx < 256u)
      vv = *(const uint4*)(in16 + ((size_t)((b * 256 + gy) * 256 + gx)) * 16 + half * 8);
    *(uint4*)&Arow[row][px][half * 8] = vv;
  }
  __syncthreads();

  f32x4 acc[4][2];
  #pragma unroll
  for (int m = 0; m < 4; ++m)
    #pragma unroll
    for (int n = 0; n < 2; ++n)
      #pragma unroll
      for (int j = 0; j < 4; ++j) acc[m][n][j] = 0.f;

  const short8* wpk8 = (const short8*)wpk;
  #pragma unroll
  for (int s = 0; s < 5; ++s) {
    int kidx = s * 2 + (lc >> 1);
    int ky = (kidx < 9) ? (kidx / 3) : 0;
    int kx = (kidx < 9) ? (kidx % 3) : 0;
    int chb = (lc & 1) * 8;
    short8 a[4], bf[2];
    #pragma unroll
    for (int m = 0; m < 4; ++m)
      a[m] = *(const short8*)&Arow[ky][pixW + m * 16 + lr + kx][chb];
    #pragma unroll
    for (int n = 0; n < 2; ++n)
      bf[n] = wpk8[(s * 4 + lc) * 64 + n0 + n * 16 + lr];
    #pragma unroll
    for (int m = 0; m < 4; ++m)
      #pragma unroll
      for (int n = 0; n < 2; ++n)
        acc[m][n] = __builtin_amdgcn_mfma_f32_16x16x32_bf16(a[m], bf[n], acc[m][n], 0, 0, 0);
  }

  __syncthreads();
  u16 (*soutp)[72] = (u16(*)[72])smem;    // 128*72*2 = 18432 <= 18720
  #pragma unroll
  for (int n = 0; n < 2; ++n) {
    const int oc = n0 + n * 16 + lr;
    const float bs = brep[oc];
    #pragma unroll
    for (int m = 0; m < 4; ++m)
      #pragma unroll
      for (int j = 0; j < 4; ++j)
        soutp[pixW + m * 16 + lc * 4 + j][oc] = f2bf(fmaxf(acc[m][n][j] + bs, 0.f));
  }
  __syncthreads();
  const size_t rowbase = (size_t)((b * 256 + h) * 256 + w0);
  for (int i = tid; i < 128 * 8; i += 256) {
    int c = i & 7, px = i >> 3;
    *(uint4*)(out + (rowbase + px) * 64 + c * 8) = *(const uint4*)&soutp[px][c * 8];
  }
}

// ---------------- 3x3 conv, CIN=64, COUT=128, MFMA, halo-row staging (pad 133).
__global__ __launch_bounds__(256, 2) void conv3x3_mfma(
    const u16* __restrict__ in, const u16* __restrict__ wpk,
    const float* __restrict__ brep, u16* __restrict__ out,
    int out_stride, int out_choff)
{
  __shared__ __align__(16) unsigned char smem[3 * 8 * 133 * 16];   // 51072 B
  uint4 (*Arow)[8][133] = (uint4(*)[8][133])smem;

  const int tid = threadIdx.x;
  const int l = tid & 63, wid = tid >> 6;
  const int bid = blockIdx.x;
  const int swz = (bid & 7) * 1024 + (bid >> 3);   // 8192 % 8 == 0 -> bijective
  const int xh = swz & 1, h = (swz >> 1) & 255, b = swz >> 9;
  const int w0 = xh * 128;

  const int waveM = wid >> 1, waveN = wid & 1;
  const int pixW = waveM * 64, n0 = waveN * 64;
  const int lr = l & 15, lc = l >> 4;

  // stage 3 rows x 130 px x 8 chunks; lanes 0-7 span c=0..7 -> banks {0,20,8,28,16,4,24,12}
  for (int i = tid; i < 3 * 130 * 8; i += 256) {
    int c = i & 7;
    int t = i >> 3;
    int px = t % 130;
    int row = t / 130;
    int gy = h + row - 1, gx = w0 + px - 1;
    uint4 vv = make_uint4(0, 0, 0, 0);
    if ((unsigned)gy < 256u && (unsigned)gx < 256u)
      vv = *(const uint4*)(in + ((size_t)((b * 256 + gy) * 256 + gx)) * 64 + c * 8);
    Arow[row][c][px] = vv;
  }
  __syncthreads();

  f32x4 acc[4][4];
  #pragma unroll
  for (int m = 0; m < 4; ++m)
    #pragma unroll
    for (int n = 0; n < 4; ++n)
      #pragma unroll
      for (int j = 0; j < 4; ++j) acc[m][n][j] = 0.f;

  const short8* wpk8 = (const short8*)wpk;
  #pragma unroll
  for (int kidx = 0; kidx < 9; ++kidx) {
    const int ky = kidx / 3, kx = kidx % 3;
    #pragma unroll
    for (int cs = 0; cs < 2; ++cs) {
      short8 a[4], bf[4];
      #pragma unroll
      for (int m = 0; m < 4; ++m)
        a[m] = *(const short8*)&Arow[ky][cs * 4 + lc][pixW + m * 16 + lr + kx];
      #pragma unroll
      for (int n = 0; n < 4; ++n)
        bf[n] = wpk8[((kidx * 2 + cs) * 4 + lc) * 128 + n0 + n * 16 + lr];
      #pragma unroll
      for (int m = 0; m < 4; ++m)
        #pragma unroll
        for (int n = 0; n < 4; ++n)
          acc[m][n] = __builtin_amdgcn_mfma_f32_16x16x32_bf16(a[m], bf[n], acc[m][n], 0, 0, 0);
    }
  }

  // epilogue: bias+relu -> LDS u16 [128][136] -> dwordx4 stores
  __syncthreads();
  u16 (*soutp)[136] = (u16(*)[136])smem;
  #pragma unroll
  for (int n = 0; n < 4; ++n) {
    const int oc = n0 + n * 16 + lr;
    const float bs = brep[oc];
    #pragma unroll
    for (int m = 0; m < 4; ++m)
      #pragma unroll
      for (int j = 0; j < 4; ++j)
        soutp[pixW + m * 16 + lc * 4 + j][oc] = f2bf(fmaxf(acc[m][n][j] + bs, 0.f));
  }
  __syncthreads();
  const size_t rowbase = (size_t)((b * 256 + h) * 256 + w0);
  for (int i = tid; i < 128 * 16; i += 256) {
    int c = i & 15, px = i >> 4;
    *(uint4*)(out + (rowbase + px) * (size_t)out_stride + out_choff + c * 8) =
        *(const uint4*)&soutp[px][c * 8];
  }
}

// ---------------- fused fconv1(256->128)+fconv2(128->64), stage-once.
// Block = 64 px, 4 waves (2M x 2N): stage1 wave 32px x 64oc, stage2 32px x 32oc.
// LDS: A_ld[32 chunks][65 px-pad] uint4 = 33280 B; f1 tile + f32 out alias it.
__global__ __launch_bounds__(256, 2) void fuse_mfma(
    const u16* __restrict__ fcat,
    const u16* __restrict__ w1p, const float* __restrict__ b1r,
    const u16* __restrict__ w2p, const float* __restrict__ b2r,
    float* __restrict__ out)
{
  __shared__ __align__(16) uint4 smem4[32 * 65];   // 33280 B
  const int tid = threadIdx.x;
  const int l = tid & 63, wid = tid >> 6;
  const int w0 = blockIdx.x * 64, hh = blockIdx.y, b = blockIdx.z;
  const int pixW = (wid >> 1) * 32;
  const int n0 = (wid & 1) * 64;
  const int lr = l & 15, lc = l >> 4;
  const size_t rowbase = (size_t)((b * 256 + hh) * 256 + w0);

  // stage 64 px x 256 ch (2048 records, 8 iters, coalesced 1KB/wave-instr)
  #pragma unroll
  for (int it = 0; it < 8; ++it) {
    int i = it * 256 + tid;
    int px = i >> 5, c = i & 31;
    smem4[c * 65 + px] = *(const uint4*)(fcat + (rowbase + px) * 256 + c * 8);
  }
  __syncthreads();

  // stage 1: K=256, 8 steps, barrier-free
  f32x4 acc[2][4];
  #pragma unroll
  for (int m = 0; m < 2; ++m)
    #pragma unroll
    for (int n = 0; n < 4; ++n)
      #pragma unroll
      for (int j = 0; j < 4; ++j) acc[m][n][j] = 0.f;

  const short8* w1p8 = (const short8*)w1p;
  #pragma unroll
  for (int ks = 0; ks < 8; ++ks) {
    short8 a[2], bf[4];
    #pragma unroll
    for (int m = 0; m < 2; ++m)
      a[m] = *(const short8*)&smem4[(ks * 4 + lc) * 65 + pixW + m * 16 + lr];
    #pragma unroll
    for (int n = 0; n < 4; ++n)
      bf[n] = w1p8[(ks * 4 + lc) * 128 + n0 + n * 16 + lr];
    #pragma unroll
    for (int m = 0; m < 2; ++m)
      #pragma unroll
      for (int n = 0; n < 4; ++n)
        acc[m][n] = __builtin_amdgcn_mfma_f32_16x16x32_bf16(a[m], bf[n], acc[m][n], 0, 0, 0);
  }
  __syncthreads();   // all stage-1 reads done

  // f1 tile -> LDS (aliases chunks 0..15 region), chunk layout [c2][65 px]
  u16* A2u = (u16*)smem4;
  #pragma unroll
  for (int n = 0; n < 4; ++n) {
    const int oc = n0 + n * 16 + lr;
    const float bs = b1r[oc];
    #pragma unroll
    for (int m = 0; m < 2; ++m)
      #pragma unroll
      for (int j = 0; j < 4; ++j) {
        int px = pixW + m * 16 + lc * 4 + j;
        A2u[((size_t)(oc >> 3) * 65 + px) * 8 + (oc & 7)] =
            f2bf(fmaxf(acc[m][n][j] + bs, 0.f));
      }
  }
  __syncthreads();

  // stage 2: K=128, 4 steps, barrier-free
  const int n02 = (wid & 1) * 32;
  f32x4 acc2[2][2];
  #pragma unroll
  for (int m = 0; m < 2; ++m)
    #pragma unroll
    for (int n = 0; n < 2; ++n)
      #pragma unroll
      for (int j = 0; j < 4; ++j) acc2[m][n][j] = 0.f;

  const short8* w2p8 = (const short8*)w2p;
  #pragma unroll
  for (int ks = 0; ks < 4; ++ks) {
    short8 a[2], bf[2];
    #pragma unroll
    for (int m = 0; m < 2; ++m)
      a[m] = *(const short8*)&smem4[(ks * 4 + lc) * 65 + pixW + m * 16 + lr];
    #pragma unroll
    for (int n = 0; n < 2; ++n)
      bf[n] = w2p8[(ks * 4 + lc) * 64 + n02 + n * 16 + lr];
    #pragma unroll
    for (int m = 0; m < 2; ++m)
      #pragma unroll
      for (int n = 0; n < 2; ++n)
        acc2[m][n] = __builtin_amdgcn_mfma_f32_16x16x32_bf16(a[m], bf[n], acc2[m][n], 0, 0, 0);
  }
  __syncthreads();   // all stage-2 reads done

  // out tile f32 [64 oc][65 px] aliases LDS; then coalesced NCHW stores
  float (*sout)[65] = (float(*)[65])smem4;   // 64*65*4 = 16640 B
  #pragma unroll
  for (int n = 0; n < 2; ++n) {
    const int oc = n02 + n * 16 + lr;
    const float bs = b2r[oc];
    #pragma unroll
    for (int m = 0; m < 2; ++m)
      #pragma unroll
      for (int j = 0; j < 4; ++j)
        sout[oc][pixW + m * 16 + lc * 4 + j] = fmaxf(acc2[m][n][j] + bs, 0.f);
  }
  __syncthreads();
  for (int i = tid; i < 64 * 64; i += 256) {
    int oc = i >> 6, px = i & 63;
    out[(((size_t)b * 64 + oc) << 16) + (size_t)hh * 256 + w0 + px] = sout[oc][px];
  }
}

extern "C" void kernel_launch(void* const* d_in, const int* in_sizes, int n_in,
                              void* d_out, int out_size, void* d_ws, size_t ws_size,
                              hipStream_t stream)
{
  const float* x   = (const float*)d_in[0];
  const float* cw1 = (const float*)d_in[1];
  const float* cb1 = (const float*)d_in[2];
  const float* cw2 = (const float*)d_in[3];
  const float* cb2 = (const float*)d_in[4];
  const float* lw1 = (const float*)d_in[5];
  const float* lb1 = (const float*)d_in[6];
  const float* lg1 = (const float*)d_in[7];
  const float* lbe1= (const float*)d_in[8];
  const float* lm1 = (const float*)d_in[9];
  const float* lv1 = (const float*)d_in[10];
  const float* lw2 = (const float*)d_in[11];
  const float* lb2 = (const float*)d_in[12];
  const float* lg2 = (const float*)d_in[13];
  const float* lbe2= (const float*)d_in[14];
  const float* lm2 = (const float*)d_in[15];
  const float* lv2 = (const float*)d_in[16];
  const float* hw1 = (const float*)d_in[17];
  const float* hb1 = (const float*)d_in[18];
  const float* hg1 = (const float*)d_in[19];
  const float* hbe1= (const float*)d_in[20];
  const float* hm1 = (const float*)d_in[21];
  const float* hv1 = (const float*)d_in[22];
  const float* hw2 = (const float*)d_in[23];
  const float* hb2 = (const float*)d_in[24];
  const float* hg2 = (const float*)d_in[25];
  const float* hbe2= (const float*)d_in[26];
  const float* hm2 = (const float*)d_in[27];
  const float* hv2 = (const float*)d_in[28];
  const float* fw1 = (const float*)d_in[29];
  const float* fb1 = (const float*)d_in[30];
  const float* fg1 = (const float*)d_in[31];
  const float* fbe1= (const float*)d_in[32];
  const float* fm1 = (const float*)d_in[33];
  const float* fv1 = (const float*)d_in[34];
  const float* fw2 = (const float*)d_in[35];
  const float* fb2 = (const float*)d_in[36];
  const float* fg2 = (const float*)d_in[37];
  const float* fbe2= (const float*)d_in[38];
  const float* fm2 = (const float*)d_in[39];
  const float* fv2 = (const float*)d_in[40];

  // ---- workspace layout with lifetime aliasing (peak ~809 MB) ----
  char* ws = (char*)d_ws;
  const size_t MB = 1024 * 1024;
  u16* lf1    = (u16*)(ws);                   // 134 MB (bconv1..lconv2)
  u16* hf1    = (u16*)(ws + 135 * MB);        // 134 MB (bconv1..hconv2)
  char* regA  = ws + 270 * MB;
  u16* low16  = (u16*)(regA);                 // 33.6 MB (front..bconv1)
  u16* high16 = (u16*)(regA + 34 * MB);       // 33.6 MB (front..bconv1)
  u16* fcat   = (u16*)(regA);                 // 537 MB, overlays low16/high16
  char* wtail = regA + 538 * MB;
  size_t woff = 0;
  auto alloc = [&](size_t bytes) -> void* {
    void* p = wtail + woff;
    woff = (woff + bytes + 255) & ~(size_t)255;
    return p;
  };
  u16* wl1p = (u16*)alloc(160*64*2);    float* bl1r = (float*)alloc(64*4);
  u16* wh1p = (u16*)alloc(160*64*2);    float* bh1r = (float*)alloc(64*4);
  u16* wl2p = (u16*)alloc(576*128*2);   float* bl2r = (float*)alloc(128*4);
  u16* wh2p = (u16*)alloc(576*128*2);   float* bh2r = (float*)alloc(128*4);
  u16* wf1p = (u16*)alloc(256*128*2);   float* bf1r = (float*)alloc(128*4);
  u16* wf2p = (u16*)alloc(128*64*2);    float* bf2r = (float*)alloc(64*4);

  // ---- weight repacks (BN folded)
  repack_pad_pack_kernel<<<40, 256, 0, stream>>>(lw1, lb1, lg1, lbe1, lm1, lv1, wl1p, bl1r, 3, 64);
  repack_pad_pack_kernel<<<40, 256, 0, stream>>>(hw1, hb1, hg1, hbe1, hm1, hv1, wh1p, bh1r, 9, 64);
  repack_pack_kernel<<<(576*128+255)/256, 256, 0, stream>>>(lw2, lb2, lg2, lbe2, lm2, lv2, wl2p, bl2r, 64, 3, 128);
  repack_pack_kernel<<<(576*128+255)/256, 256, 0, stream>>>(hw2, hb2, hg2, hbe2, hm2, hv2, wh2p, bh2r, 64, 3, 128);
  repack_pack_kernel<<<(256*128+255)/256, 256, 0, stream>>>(fw1, fb1, fg1, fbe1, fm1, fv1, wf1p, bf1r, 256, 1, 128);
  repack_pack_kernel<<<(128*64+255)/256,  256, 0, stream>>>(fw2, fb2, fg2, fbe2, fm2, fv2, wf2p, bf2r, 128, 1, 64);

  // ---- front: x -> low16, high16 (bf16 ch16-padded NHWC)
  front_kernel<<<4096, 256, 0, stream>>>(x, cw1, cb1, cw2, cb2, low16, high16);

  // ---- branch conv1s (MFMA, K=160 padded)
  conv3x3s_mfma<<<8192, 256, 0, stream>>>(low16,  wl1p, bl1r, lf1);
  conv3x3s_mfma<<<8192, 256, 0, stream>>>(high16, wh1p, bh1r, hf1);

  // ---- big 3x3 convs: halo-staged MFMA (XCD-swizzled)
  conv3x3_mfma<<<8192, 256, 0, stream>>>(lf1, wl2p, bl2r, fcat, 256, 0);
  conv3x3_mfma<<<8192, 256, 0, stream>>>(hf1, wh2p, bh2r, fcat, 256, 128);

  // ---- fused fuse-stage (stage-once, barrier-free K-loops)
  dim3 fgrid(4, 256, 16);
  fuse_mfma<<<fgrid, 256, 0, stream>>>(fcat, wf1p, bf1r, wf2p, bf2r, (float*)d_out);
}

// Round 6
// 964.281 us; speedup vs baseline: 10.7877x; 1.0885x over previous
//
#include <hip/hip_runtime.h>
#include <hip/hip_bf16.h>

// FrequencyInflammationDetector — round 6.
// R5 profile: conv3x3_mfma 228us, ALL pipes <30% (MfmaUtil 28.6, VALU 23.8,
// HBM 18, Occ 32) -> latency-bound: per-step L2 weight loads (~300cy) with no
// prefetch depth (VGPR 68) + reg-staged LDS writes.
// Fixes: (1) global_load_lds staging with linear LDS + XOR chunk swizzle
// (pre-swizzled global source, zero-guard page for conv padding);
// (2) explicit 3-buffer rotating weight prefetch (depth-2, static indices);
// (3) same treatment for fuse_mfma.

#define EPS_BN 1e-5f

typedef unsigned int u32;
typedef unsigned short u16;
typedef __attribute__((ext_vector_type(8))) short short8;
typedef __attribute__((ext_vector_type(4))) float f32x4;

__device__ __forceinline__ u16 f2bf(float f) {
  u32 u = __float_as_uint(f);
  u32 r = (u + 0x7fffu + ((u >> 16) & 1u)) >> 16;   // RNE
  return (u16)r;
}

__device__ __forceinline__ void gload_lds16(const void* g, void* l) {
  __builtin_amdgcn_global_load_lds(
      (const __attribute__((address_space(1))) void*)g,
      (__attribute__((address_space(3))) void*)l, 16, 0, 0);
}

// ---------------- repack to MFMA fragment layout (bf16, BN folded)
__global__ __launch_bounds__(256) void repack_pack_kernel(
    const float* __restrict__ w, const float* __restrict__ bias,
    const float* __restrict__ g, const float* __restrict__ be,
    const float* __restrict__ m, const float* __restrict__ v,
    u16* __restrict__ wpk, float* __restrict__ brep,
    int CIN, int KHW, int COUT)
{
  int idx = blockIdx.x * 256 + threadIdx.x;
  int K = CIN * KHW * KHW;
  if (idx < K * COUT) {
    int oc = idx % COUT;
    int k  = idx / COUT;
    int ic = k % CIN;
    int kidx = k / CIN;
    int ky = kidx / KHW, kx = kidx % KHW;
    float alpha = g[oc] * rsqrtf(v[oc] + EPS_BN);
    float val = w[(((size_t)oc * CIN + ic) * KHW + ky) * KHW + kx] * alpha;
    int ks = k >> 5, c = (k >> 3) & 3, e = k & 7;
    wpk[((size_t)((ks * 4 + c) * COUT + oc)) * 8 + e] = f2bf(val);
  }
  if (idx < COUT) {
    float alpha = g[idx] * rsqrtf(v[idx] + EPS_BN);
    brep[idx] = fmaf(bias[idx], alpha, be[idx] - m[idx] * alpha);
  }
}

// ---------------- repack for branch conv1: K padded to 160 (kidx 0..9, ic 0..15)
__global__ __launch_bounds__(256) void repack_pad_pack_kernel(
    const float* __restrict__ w, const float* __restrict__ bias,
    const float* __restrict__ g, const float* __restrict__ be,
    const float* __restrict__ m, const float* __restrict__ v,
    u16* __restrict__ wpk, float* __restrict__ brep, int CIN, int COUT)
{
  int idx = blockIdx.x * 256 + threadIdx.x;
  if (idx < 160 * COUT) {
    int oc = idx % COUT;
    int k  = idx / COUT;
    int kidx = k >> 4, ic = k & 15;
    float val = 0.f;
    if (kidx < 9 && ic < CIN) {
      int ky = kidx / 3, kx = kidx % 3;
      float alpha = g[oc] * rsqrtf(v[oc] + EPS_BN);
      val = w[(((size_t)oc * CIN + ic) * 3 + ky) * 3 + kx] * alpha;
    }
    int ks = k >> 5, c = (k >> 3) & 3, e = k & 7;
    wpk[((size_t)((ks * 4 + c) * COUT + oc)) * 8 + e] = f2bf(val);
  }
  if (idx < COUT) {
    float alpha = g[idx] * rsqrtf(v[idx] + EPS_BN);
    brep[idx] = fmaf(bias[idx], alpha, be[idx] - m[idx] * alpha);
  }
}

// ---------------- front: 1x1 -> relu -> 1x1 -> haar. Out: bf16 NHWC ch16-padded.
__global__ __launch_bounds__(256) void front_kernel(
    const float* __restrict__ x,
    const float* __restrict__ cw1, const float* __restrict__ cb1,
    const float* __restrict__ cw2, const float* __restrict__ cb2,
    u16* __restrict__ low16, u16* __restrict__ high16)
{
  const int pid = blockIdx.x * 256 + threadIdx.x;
  const int wo = pid & 255, ho = (pid >> 8) & 255, b = pid >> 16;
  float hsv[2][2][3];
  #pragma unroll
  for (int dy = 0; dy < 2; ++dy) {
    #pragma unroll
    for (int dx = 0; dx < 2; ++dx) {
      int h = 2 * ho + dy, w = 2 * wo + dx;
      size_t base = ((size_t)(b * 3) << 18) + (size_t)h * 512 + w;
      float p0 = x[base];
      float p1 = x[base + (1u << 18)];
      float p2 = x[base + (2u << 18)];
      float o0 = cb2[0], o1 = cb2[1], o2 = cb2[2];
      #pragma unroll
      for (int o = 0; o < 16; ++o) {
        float t = fmaf(cw1[o*3+2], p2, fmaf(cw1[o*3+1], p1, fmaf(cw1[o*3+0], p0, cb1[o])));
        t = fmaxf(t, 0.f);
        o0 = fmaf(cw2[o],      t, o0);
        o1 = fmaf(cw2[16 + o], t, o1);
        o2 = fmaf(cw2[32 + o], t, o2);
      }
      hsv[dy][dx][0] = o0; hsv[dy][dx][1] = o1; hsv[dy][dx][2] = o2;
    }
  }
  u16 lrec[16], hrec[16];
  #pragma unroll
  for (int i = 0; i < 16; ++i) { lrec[i] = 0; hrec[i] = 0; }
  #pragma unroll
  for (int c = 0; c < 3; ++c) {
    float a  = hsv[0][0][c], bb = hsv[0][1][c];
    float cc = hsv[1][0][c], dd = hsv[1][1][c];
    lrec[c]         = f2bf((a + bb + cc + dd) * 0.5f);
    hrec[c * 3 + 0] = f2bf((a + bb - cc - dd) * 0.5f);
    hrec[c * 3 + 1] = f2bf((a - bb + cc - dd) * 0.5f);
    hrec[c * 3 + 2] = f2bf((a - bb - cc + dd) * 0.5f);
  }
  *(uint4*)(low16  + (size_t)pid * 16)     = *(const uint4*)&lrec[0];
  *(uint4*)(low16  + (size_t)pid * 16 + 8) = *(const uint4*)&lrec[8];
  *(uint4*)(high16 + (size_t)pid * 16)     = *(const uint4*)&hrec[0];
  *(uint4*)(high16 + (size_t)pid * 16 + 8) = *(const uint4*)&hrec[8];
}

// ---------------- branch conv1 (3x3, CIN<=16 padded, COUT=64), MFMA, halo rows.
__global__ __launch_bounds__(256) void conv3x3s_mfma(
    const u16* __restrict__ in16, const u16* __restrict__ wpk,
    const float* __restrict__ brep, u16* __restrict__ out)
{
  __shared__ __align__(16) u16 smem[3 * 130 * 24];
  u16 (*Arow)[130][24] = (u16(*)[130][24])smem;

  const int tid = threadIdx.x;
  const int l = tid & 63, wid = tid >> 6;
  const int bid = blockIdx.x;
  const int swz = (bid & 7) * 1024 + (bid >> 3);
  const int xh = swz & 1, h = (swz >> 1) & 255, b = swz >> 9;
  const int w0 = xh * 128;
  const int pixW = (wid >> 1) * 64, n0 = (wid & 1) * 32;
  const int lr = l & 15, lc = l >> 4;

  for (int i = tid; i < 3 * 130 * 2; i += 256) {
    int half = i & 1, rec = i >> 1;
    int px = rec % 130, row = rec / 130;
    int gy = h + row - 1, gx = w0 + px - 1;
    uint4 vv = make_uint4(0, 0, 0, 0);
    if ((unsigned)gy < 256u && (unsigned)gx < 256u)
      vv = *(const uint4*)(in16 + ((size_t)((b * 256 + gy) * 256 + gx)) * 16 + half * 8);
    *(uint4*)&Arow[row][px][half * 8] = vv;
  }
  __syncthreads();

  f32x4 acc[4][2];
  #pragma unroll
  for (int m = 0; m < 4; ++m)
    #pragma unroll
    for (int n = 0; n < 2; ++n)
      #pragma unroll
      for (int j = 0; j < 4; ++j) acc[m][n][j] = 0.f;

  const short8* wpk8 = (const short8*)wpk;
  #pragma unroll
  for (int s = 0; s < 5; ++s) {
    int kidx = s * 2 + (lc >> 1);
    int ky = (kidx < 9) ? (kidx / 3) : 0;
    int kx = (kidx < 9) ? (kidx % 3) : 0;
    int chb = (lc & 1) * 8;
    short8 a[4], bf[2];
    #pragma unroll
    for (int m = 0; m < 4; ++m)
      a[m] = *(const short8*)&Arow[ky][pixW + m * 16 + lr + kx][chb];
    #pragma unroll
    for (int n = 0; n < 2; ++n)
      bf[n] = wpk8[(s * 4 + lc) * 64 + n0 + n * 16 + lr];
    #pragma unroll
    for (int m = 0; m < 4; ++m)
      #pragma unroll
      for (int n = 0; n < 2; ++n)
        acc[m][n] = __builtin_amdgcn_mfma_f32_16x16x32_bf16(a[m], bf[n], acc[m][n], 0, 0, 0);
  }

  __syncthreads();
  u16 (*soutp)[72] = (u16(*)[72])smem;
  #pragma unroll
  for (int n = 0; n < 2; ++n) {
    const int oc = n0 + n * 16 + lr;
    const float bs = brep[oc];
    #pragma unroll
    for (int m = 0; m < 4; ++m)
      #pragma unroll
      for (int j = 0; j < 4; ++j)
        soutp[pixW + m * 16 + lc * 4 + j][oc] = f2bf(fmaxf(acc[m][n][j] + bs, 0.f));
  }
  __syncthreads();
  const size_t rowbase = (size_t)((b * 256 + h) * 256 + w0);
  for (int i = tid; i < 128 * 8; i += 256) {
    int c = i & 7, px = i >> 3;
    *(uint4*)(out + (rowbase + px) * 64 + c * 8) = *(const uint4*)&soutp[px][c * 8];
  }
}

// ---------------- 3x3 conv, CIN=64, COUT=128, MFMA.
// Staging: global_load_lds width=16, linear LDS [row][px][chunk-slot] with
// chunk swizzle slot = chunk ^ (px&7) applied on the GLOBAL source (within the
// same 128B record -> coalescing preserved). OOB lanes -> zero guard page.
// K-loop: 18 steps, 3-buffer rotating weight prefetch (depth 2).
__global__ __launch_bounds__(256, 2) void conv3x3_mfma(
    const u16* __restrict__ in, const u16* __restrict__ wpk,
    const float* __restrict__ brep, u16* __restrict__ out,
    const u16* __restrict__ zpg, int out_stride, int out_choff)
{
  __shared__ __align__(16) unsigned char smem[53248];   // 13*256*16 (3*1040 used)

  const int tid = threadIdx.x;
  const int l = tid & 63, wid = tid >> 6;
  const int bid = blockIdx.x;
  const int swz = (bid & 7) * 1024 + (bid >> 3);   // 8192 % 8 == 0 -> bijective
  const int xh = swz & 1, h = (swz >> 1) & 255, b = swz >> 9;
  const int w0 = xh * 128;
  const int pixW = (wid >> 1) * 64, n0 = (wid & 1) * 64;
  const int lr = l & 15, lc = l >> 4;

  // stage 3 halo rows: slot i=(row*1040 + px*8 + cslot); element chunk = cslot^(px&7)
  #pragma unroll
  for (int it = 0; it < 13; ++it) {
    int i = it * 256 + tid;
    int row = i / 1040;
    int rem = i - row * 1040;
    int px = rem >> 3, cslot = rem & 7;
    int gy = h + row - 1, gx = w0 + px - 1;
    bool ok = ((unsigned)gy < 256u) && ((unsigned)gx < 256u);
    const u16* src = ok
        ? in + ((size_t)((b * 256 + gy) * 256 + gx)) * 64 + (cslot ^ (px & 7)) * 8
        : zpg;
    gload_lds16(src, smem + (size_t)i * 16);
  }
  __syncthreads();

  f32x4 acc[4][4];
  #pragma unroll
  for (int m = 0; m < 4; ++m)
    #pragma unroll
    for (int n = 0; n < 4; ++n)
      #pragma unroll
      for (int j = 0; j < 4; ++j) acc[m][n][j] = 0.f;

  const short8* wpk8 = (const short8*)wpk;
  auto ldw = [&](short8* buf, int s) {
    #pragma unroll
    for (int n = 0; n < 4; ++n)
      buf[n] = wpk8[(size_t)(s * 4 + lc) * 128 + n0 + n * 16 + lr];
  };
  auto lda = [&](short8* a, int s) {
    const int kidx = s >> 1, cs = s & 1;
    const int ky = kidx / 3, kx = kidx % 3;
    #pragma unroll
    for (int m = 0; m < 4; ++m) {
      int px = pixW + m * 16 + lr + kx;
      int slot = ky * 1040 + px * 8 + ((cs * 4 + lc) ^ (px & 7));
      a[m] = *(const short8*)(smem + (size_t)slot * 16);
    }
  };

  short8 w0b[4], w1b[4], w2b[4];
  ldw(w0b, 0); ldw(w1b, 1);
  #pragma unroll
  for (int s = 0; s < 18; ++s) {
    short8 a[4];
    lda(a, s);
    if (s < 16) ldw((s % 3 == 0) ? w2b : (s % 3 == 1) ? w0b : w1b, s + 2);
    const short8* wc = (s % 3 == 0) ? w0b : (s % 3 == 1) ? w1b : w2b;
    #pragma unroll
    for (int m = 0; m < 4; ++m)
      #pragma unroll
      for (int n = 0; n < 4; ++n)
        acc[m][n] = __builtin_amdgcn_mfma_f32_16x16x32_bf16(a[m], wc[n], acc[m][n], 0, 0, 0);
  }

  // epilogue: bias+relu -> LDS u16 [128][136] -> dwordx4 stores
  __syncthreads();
  u16 (*soutp)[136] = (u16(*)[136])smem;
  #pragma unroll
  for (int n = 0; n < 4; ++n) {
    const int oc = n0 + n * 16 + lr;
    const float bs = brep[oc];
    #pragma unroll
    for (int m = 0; m < 4; ++m)
      #pragma unroll
      for (int j = 0; j < 4; ++j)
        soutp[pixW + m * 16 + lc * 4 + j][oc] = f2bf(fmaxf(acc[m][n][j] + bs, 0.f));
  }
  __syncthreads();
  const size_t rowbase = (size_t)((b * 256 + h) * 256 + w0);
  for (int i = tid; i < 128 * 16; i += 256) {
    int c = i & 15, px = i >> 4;
    *(uint4*)(out + (rowbase + px) * (size_t)out_stride + out_choff + c * 8) =
        *(const uint4*)&soutp[px][c * 8];
  }
}

// ---------------- fused fconv1(256->128)+fconv2(128->64), stage-once.
// Staging via global_load_lds, LDS [px][32 chunk-slots], slot = chunk^(px&7).
__global__ __launch_bounds__(256, 2) void fuse_mfma(
    const u16* __restrict__ fcat,
    const u16* __restrict__ w1p, const float* __restrict__ b1r,
    const u16* __restrict__ w2p, const float* __restrict__ b2r,
    float* __restrict__ out)
{
  __shared__ __align__(16) unsigned char smem[33280];   // 32KB stage (+pad); A2/sout alias
  const int tid = threadIdx.x;
  const int l = tid & 63, wid = tid >> 6;
  const int w0 = blockIdx.x * 64, hh = blockIdx.y, b = blockIdx.z;
  const int pixW = (wid >> 1) * 32;
  const int n0 = (wid & 1) * 64;
  const int n02 = (wid & 1) * 32;
  const int lr = l & 15, lc = l >> 4;
  const size_t rowbase = (size_t)((b * 256 + hh) * 256 + w0);

  // stage 64 px x 256 ch: slot i = px*32 + cslot; element chunk = cslot^(px&7)
  #pragma unroll
  for (int it = 0; it < 8; ++it) {
    int i = it * 256 + tid;
    int px = i >> 5, cslot = i & 31;
    const u16* src = fcat + (rowbase + px) * 256 + (cslot ^ (px & 7)) * 8;
    gload_lds16(src, smem + (size_t)i * 16);
  }
  __syncthreads();

  // stage 1: K=256, 8 steps, 3-buffer weight prefetch
  f32x4 acc[2][4];
  #pragma unroll
  for (int m = 0; m < 2; ++m)
    #pragma unroll
    for (int n = 0; n < 4; ++n)
      #pragma unroll
      for (int j = 0; j < 4; ++j) acc[m][n][j] = 0.f;

  const short8* w1p8 = (const short8*)w1p;
  auto ldw1 = [&](short8* buf, int s) {
    #pragma unroll
    for (int n = 0; n < 4; ++n)
      buf[n] = w1p8[(size_t)(s * 4 + lc) * 128 + n0 + n * 16 + lr];
  };
  auto lda1 = [&](short8* a, int ks) {
    #pragma unroll
    for (int m = 0; m < 2; ++m) {
      int px = pixW + m * 16 + lr;
      int slot = px * 32 + ((ks * 4 + lc) ^ (px & 7));
      a[m] = *(const short8*)(smem + (size_t)slot * 16);
    }
  };

  short8 w0b[4], w1b[4], w2b[4];
  ldw1(w0b, 0); ldw1(w1b, 1);
  #pragma unroll
  for (int s = 0; s < 8; ++s) {
    short8 a[2];
    lda1(a, s);
    if (s < 6) ldw1((s % 3 == 0) ? w2b : (s % 3 == 1) ? w0b : w1b, s + 2);
    const short8* wc = (s % 3 == 0) ? w0b : (s % 3 == 1) ? w1b : w2b;
    #pragma unroll
    for (int m = 0; m < 2; ++m)
      #pragma unroll
      for (int n = 0; n < 4; ++n)
        acc[m][n] = __builtin_amdgcn_mfma_f32_16x16x32_bf16(a[m], wc[n], acc[m][n], 0, 0, 0);
  }

  // prefetch ALL stage-2 weights (16KB, L2-hot) while epilogue runs
  const short8* w2p8 = (const short8*)w2p;
  short8 wf2[4][2];
  #pragma unroll
  for (int ks = 0; ks < 4; ++ks)
    #pragma unroll
    for (int n = 0; n < 2; ++n)
      wf2[ks][n] = w2p8[(ks * 4 + lc) * 64 + n02 + n * 16 + lr];

  __syncthreads();   // all stage-1 LDS reads done

  // f1 tile -> LDS, chunk layout A2[c2][65 px] (aliases staging region)
  uint4* smem4 = (uint4*)smem;
  u16* A2u = (u16*)smem;
  #pragma unroll
  for (int n = 0; n < 4; ++n) {
    const int oc = n0 + n * 16 + lr;
    const float bs = b1r[oc];
    #pragma unroll
    for (int m = 0; m < 2; ++m)
      #pragma unroll
      for (int j = 0; j < 4; ++j) {
        int px = pixW + m * 16 + lc * 4 + j;
        A2u[((size_t)(oc >> 3) * 65 + px) * 8 + (oc & 7)] =
            f2bf(fmaxf(acc[m][n][j] + bs, 0.f));
      }
  }
  __syncthreads();

  // stage 2: K=128, 4 steps, weights already in regs
  f32x4 acc2[2][2];
  #pragma unroll
  for (int m = 0; m < 2; ++m)
    #pragma unroll
    for (int n = 0; n < 2; ++n)
      #pragma unroll
      for (int j = 0; j < 4; ++j) acc2[m][n][j] = 0.f;

  #pragma unroll
  for (int ks = 0; ks < 4; ++ks) {
    short8 a[2];
    #pragma unroll
    for (int m = 0; m < 2; ++m)
      a[m] = *(const short8*)&smem4[(ks * 4 + lc) * 65 + pixW + m * 16 + lr];
    #pragma unroll
    for (int m = 0; m < 2; ++m)
      #pragma unroll
      for (int n = 0; n < 2; ++n)
        acc2[m][n] = __builtin_amdgcn_mfma_f32_16x16x32_bf16(a[m], wf2[ks][n], acc2[m][n], 0, 0, 0);
  }
  __syncthreads();   // all stage-2 reads done before sout alias write

  float (*sout)[65] = (float(*)[65])smem;   // 64*65*4 = 16640 B
  #pragma unroll
  for (int n = 0; n < 2; ++n) {
    const int oc = n02 + n * 16 + lr;
    const float bs = b2r[oc];
    #pragma unroll
    for (int m = 0; m < 2; ++m)
      #pragma unroll
      for (int j = 0; j < 4; ++j)
        sout[oc][pixW + m * 16 + lc * 4 + j] = fmaxf(acc2[m][n][j] + bs, 0.f);
  }
  __syncthreads();
  for (int i = tid; i < 64 * 64; i += 256) {
    int oc = i >> 6, px = i & 63;
    out[(((size_t)b * 64 + oc) << 16) + (size_t)hh * 256 + w0 + px] = sout[oc][px];
  }
}

extern "C" void kernel_launch(void* const* d_in, const int* in_sizes, int n_in,
                              void* d_out, int out_size, void* d_ws, size_t ws_size,
                              hipStream_t stream)
{
  const float* x   = (const float*)d_in[0];
  const float* cw1 = (const float*)d_in[1];
  const float* cb1 = (const float*)d_in[2];
  const float* cw2 = (const float*)d_in[3];
  const float* cb2 = (const float*)d_in[4];
  const float* lw1 = (const float*)d_in[5];
  const float* lb1 = (const float*)d_in[6];
  const float* lg1 = (const float*)d_in[7];
  const float* lbe1= (const float*)d_in[8];
  const float* lm1 = (const float*)d_in[9];
  const float* lv1 = (const float*)d_in[10];
  const float* lw2 = (const float*)d_in[11];
  const float* lb2 = (const float*)d_in[12];
  const float* lg2 = (const float*)d_in[13];
  const float* lbe2= (const float*)d_in[14];
  const float* lm2 = (const float*)d_in[15];
  const float* lv2 = (const float*)d_in[16];
  const float* hw1 = (const float*)d_in[17];
  const float* hb1 = (const float*)d_in[18];
  const float* hg1 = (const float*)d_in[19];
  const float* hbe1= (const float*)d_in[20];
  const float* hm1 = (const float*)d_in[21];
  const float* hv1 = (const float*)d_in[22];
  const float* hw2 = (const float*)d_in[23];
  const float* hb2 = (const float*)d_in[24];
  const float* hg2 = (const float*)d_in[25];
  const float* hbe2= (const float*)d_in[26];
  const float* hm2 = (const float*)d_in[27];
  const float* hv2 = (const float*)d_in[28];
  const float* fw1 = (const float*)d_in[29];
  const float* fb1 = (const float*)d_in[30];
  const float* fg1 = (const float*)d_in[31];
  const float* fbe1= (const float*)d_in[32];
  const float* fm1 = (const float*)d_in[33];
  const float* fv1 = (const float*)d_in[34];
  const float* fw2 = (const float*)d_in[35];
  const float* fb2 = (const float*)d_in[36];
  const float* fg2 = (const float*)d_in[37];
  const float* fbe2= (const float*)d_in[38];
  const float* fm2 = (const float*)d_in[39];
  const float* fv2 = (const float*)d_in[40];

  // ---- workspace layout with lifetime aliasing (peak ~809 MB) ----
  char* ws = (char*)d_ws;
  const size_t MB = 1024 * 1024;
  u16* lf1    = (u16*)(ws);                   // 134 MB (bconv1..lconv2)
  u16* hf1    = (u16*)(ws + 135 * MB);        // 134 MB (bconv1..hconv2)
  char* regA  = ws + 270 * MB;
  u16* low16  = (u16*)(regA);                 // 33.6 MB (front..bconv1)
  u16* high16 = (u16*)(regA + 34 * MB);       // 33.6 MB (front..bconv1)
  u16* fcat   = (u16*)(regA);                 // 537 MB, overlays low16/high16
  char* wtail = regA + 538 * MB;
  size_t woff = 0;
  auto alloc = [&](size_t bytes) -> void* {
    void* p = wtail + woff;
    woff = (woff + bytes + 255) & ~(size_t)255;
    return p;
  };
  u16* wl1p = (u16*)alloc(160*64*2);    float* bl1r = (float*)alloc(64*4);
  u16* wh1p = (u16*)alloc(160*64*2);    float* bh1r = (float*)alloc(64*4);
  u16* wl2p = (u16*)alloc(576*128*2);   float* bl2r = (float*)alloc(128*4);
  u16* wh2p = (u16*)alloc(576*128*2);   float* bh2r = (float*)alloc(128*4);
  u16* wf1p = (u16*)alloc(256*128*2);   float* bf1r = (float*)alloc(128*4);
  u16* wf2p = (u16*)alloc(128*64*2);    float* bf2r = (float*)alloc(64*4);
  u16* zpg  = (u16*)alloc(256);         // zero guard page for OOB gload_lds

  hipMemsetAsync(zpg, 0, 256, stream);

  // ---- weight repacks (BN folded)
  repack_pad_pack_kernel<<<40, 256, 0, stream>>>(lw1, lb1, lg1, lbe1, lm1, lv1, wl1p, bl1r, 3, 64);
  repack_pad_pack_kernel<<<40, 256, 0, stream>>>(hw1, hb1, hg1, hbe1, hm1, hv1, wh1p, bh1r, 9, 64);
  repack_pack_kernel<<<(576*128+255)/256, 256, 0, stream>>>(lw2, lb2, lg2, lbe2, lm2, lv2, wl2p, bl2r, 64, 3, 128);
  repack_pack_kernel<<<(576*128+255)/256, 256, 0, stream>>>(hw2, hb2, hg2, hbe2, hm2, hv2, wh2p, bh2r, 64, 3, 128);
  repack_pack_kernel<<<(256*128+255)/256, 256, 0, stream>>>(fw1, fb1, fg1, fbe1, fm1, fv1, wf1p, bf1r, 256, 1, 128);
  repack_pack_kernel<<<(128*64+255)/256,  256, 0, stream>>>(fw2, fb2, fg2, fbe2, fm2, fv2, wf2p, bf2r, 128, 1, 64);

  // ---- front: x -> low16, high16 (bf16 ch16-padded NHWC)
  front_kernel<<<4096, 256, 0, stream>>>(x, cw1, cb1, cw2, cb2, low16, high16);

  // ---- branch conv1s (MFMA, K=160 padded)
  conv3x3s_mfma<<<8192, 256, 0, stream>>>(low16,  wl1p, bl1r, lf1);
  conv3x3s_mfma<<<8192, 256, 0, stream>>>(high16, wh1p, bh1r, hf1);

  // ---- big 3x3 convs: gload_lds-staged MFMA (XCD-swizzled)
  conv3x3_mfma<<<8192, 256, 0, stream>>>(lf1, wl2p, bl2r, fcat, zpg, 256, 0);
  conv3x3_mfma<<<8192, 256, 0, stream>>>(hf1, wh2p, bh2r, fcat, zpg, 256, 128);

  // ---- fused fuse-stage
  dim3 fgrid(4, 256, 16);
  fuse_mfma<<<fgrid, 256, 0, stream>>>(fcat, wf1p, bf1r, wf2p, bf2r, (float*)d_out);
}